// Round 8
// baseline (205.898 us; speedup 1.0000x reference)
//
#include <hip/hip_runtime.h>
#include <hip/hip_bf16.h>

// B=32, T=1024, D=256 fixed by the reference problem.
typedef __attribute__((ext_vector_type(8))) short bf16x8;
typedef __attribute__((ext_vector_type(4))) float f32x4;

#define INVT (1.0f/0.07f)

static __device__ __forceinline__ short f2bf(float f){
    unsigned int u = __float_as_uint(f);
    unsigned int r = (u + 0x7fffu + ((u >> 16) & 1u)) >> 16;
    return (short)r;
}
static __device__ __forceinline__ float bf2f(short s){
    return __uint_as_float(((unsigned int)(unsigned short)s) << 16);
}

// async global->LDS, 16B per lane; LDS dest = wave-uniform base + lane*16
static __device__ __forceinline__ void gld16(const void* g, void* l){
    __builtin_amdgcn_global_load_lds(
        (const __attribute__((address_space(1))) unsigned int*)g,
        (__attribute__((address_space(3))) unsigned int*)l, 16, 0, 0);
}

// ---- prep: blocks 0..511 convert W to bf16; blocks 512..543 per-batch rank scan + zero bsum
__global__ __launch_bounds__(256) void prep_kernel(const float* __restrict__ Weeg,
                                                   const float* __restrict__ Weye,
                                                   const int* __restrict__ mask,
                                                   short* __restrict__ Wout,
                                                   int* __restrict__ rank,
                                                   int* __restrict__ idx,
                                                   int* __restrict__ Tv,
                                                   float* __restrict__ cb,
                                                   float* __restrict__ bsum){
    __shared__ int ssum[256];
    int tid = threadIdx.x;
    if (blockIdx.x < 512){
        int i = blockIdx.x * 256 + tid;
        float v = (i < 65536) ? Weeg[i] : Weye[i - 65536];
        Wout[i] = f2bf(v);
        return;
    }
    int b = blockIdx.x - 512;
    if (tid == 0) bsum[b] = 0.f;
    int local[4]; int s = 0;
    #pragma unroll
    for (int q = 0; q < 4; ++q){
        int t = tid*4 + q;
        local[q] = (mask[b*1024 + t] > 0) ? 1 : 0;
        s += local[q];
    }
    ssum[tid] = s;
    __syncthreads();
    for (int off = 1; off < 256; off <<= 1){
        int add = (tid >= off) ? ssum[tid - off] : 0;
        __syncthreads();
        ssum[tid] += add;
        __syncthreads();
    }
    int run = ssum[tid] - s;
    #pragma unroll
    for (int q = 0; q < 4; ++q){
        int t = tid*4 + q;
        int g = b*1024 + t;
        run += local[q];
        rank[g] = run - 1;
        cb[g]   = local[q] ? 0.0f : -1e9f;
        if (local[q]) idx[b*1024 + run - 1] = t;
    }
    if (tid == 255) Tv[b] = ssum[255];
}

// ---- fused projection + L2 normalize, both modalities (blockIdx.y selects).
// W staged via global_load_lds(16B) into XOR-swizzled unpadded LDS (32 KB).
__global__ __launch_bounds__(256, 5) void proj_kernel(const float* __restrict__ Aeeg,
                                                      const float* __restrict__ Aeye,
                                                      const short* __restrict__ Wbf,
                                                      short* __restrict__ Eout,
                                                      short* __restrict__ Vout){
    __shared__ short sW[64 * 256];     // unpadded; XOR-swizzled in 16B blocks
    int sel = blockIdx.y;
    const float* A   = sel ? Aeye : Aeeg;
    const short* W   = Wbf + sel * 65536;
    short*       Out = sel ? Vout : Eout;

    int tid = threadIdx.x;
    int w = tid >> 6, lane = tid & 63;
    int l15 = lane & 15, lq = lane >> 4;
    int kb  = lq * 8;
    int row0 = blockIdx.x * 64;

    // X-row fragments (B-operand), f32 -> bf16
    bf16x8 xf[8];
    {
        const float* ap = A + (size_t)(row0 + w*16 + l15) * 256 + kb;
        #pragma unroll
        for (int g = 0; g < 8; ++g){
            float4 x0 = *(const float4*)(ap + g*32);
            float4 x1 = *(const float4*)(ap + g*32 + 4);
            bf16x8 t;
            t[0]=f2bf(x0.x); t[1]=f2bf(x0.y); t[2]=f2bf(x0.z); t[3]=f2bf(x0.w);
            t[4]=f2bf(x1.x); t[5]=f2bf(x1.y); t[6]=f2bf(x1.z); t[7]=f2bf(x1.w);
            xf[g] = t;
        }
    }

    f32x4 acc[16];
    #pragma unroll
    for (int q = 0; q < 16; ++q) acc[q] = (f32x4){0.f,0.f,0.f,0.f};

    int ro   = lane >> 5;        // 0..1: row within a 1KB gld16 issue
    int cb_s = lane & 31;        // 16B col-block within a 512B row
    int s7   = l15 & 7;

    #pragma unroll
    for (int pass = 0; pass < 4; ++pass){
        if (pass) __syncthreads();
        // stage W rows [pass*64, +64): each wave 16 rows, 2 rows per issue
        #pragma unroll
        for (int p = 0; p < 8; ++p){
            int rl  = w*16 + p*2 + ro;                 // LDS row index
            int cbg = cb_s ^ ((p*2 + ro) & 7);         // swizzled global col-block
            gld16(W + (size_t)(pass*64 + rl)*256 + cbg*8,
                  &sW[(w*16 + p*2) * 256]);
        }
        __syncthreads();
        #pragma unroll
        for (int nt = 0; nt < 4; ++nt){
            f32x4 c = acc[pass*4 + nt];
            int rbase = (nt*16 + l15) * 256;
            #pragma unroll
            for (int g = 0; g < 8; ++g){
                bf16x8 wf = *(const bf16x8*)&sW[rbase + (((g*4 + lq) ^ s7) << 3)];
                c = __builtin_amdgcn_mfma_f32_16x16x32_bf16(wf, xf[g], c, 0, 0, 0);
            }
            acc[pass*4 + nt] = c;
        }
    }

    // D[e][xrow]: lane holds xrow = l15, e = (pass*4+nt)*16 + lq*4 + r
    float ss = 0.f;
    #pragma unroll
    for (int q = 0; q < 16; ++q){
        #pragma unroll
        for (int r = 0; r < 4; ++r){ float x = acc[q][r]; ss += x*x; }
    }
    ss += __shfl_xor(ss, 16);
    ss += __shfl_xor(ss, 32);
    float scale = 1.0f / fmaxf(sqrtf(ss), 1e-12f);

    short* op = Out + (size_t)(row0 + w*16 + l15) * 256 + lq*4;
    #pragma unroll
    for (int q = 0; q < 16; ++q){
        short4 pk;
        pk.x = f2bf(acc[q][0] * scale);
        pk.y = f2bf(acc[q][1] * scale);
        pk.z = f2bf(acc[q][2] * scale);
        pk.w = f2bf(acc[q][3] * scale);
        *(short4*)(op + ((q >> 2) * 64 + (q & 3) * 16)) = pk;
    }
}

// ---- loss: LDS-free register GEMM. No barriers, no LDS, no wave coupling.
// Grid 1024 (XCD-pinned: batch b's 32 blocks on XCD b%8). Block = 4 independent
// waves; wave = 32 i-rows (A-frags in 64 VGPRs, loaded once from global) x one
// 256-col j-slice. V-fragments streamed directly from (XCD-local) L2; per j-tile:
// 8 independent dwordx4 loads, 16 MFMAs, 8 exp. Partial sums -> psum[b][js][i].
__global__ __launch_bounds__(256) void loss_kernel(const short* __restrict__ E,
                                                   const short* __restrict__ V,
                                                   const float* __restrict__ cb,
                                                   float* __restrict__ psum){
    // decode: xcd = n&7; m = n>>3 (0..127); b = (m>>5)*8 + xcd; r = m&31
    int n   = blockIdx.x;
    int m   = n >> 3;
    int b   = ((m >> 5) << 3) | (n & 7);
    int r   = m & 31;
    int i0  = (r >> 2) * 128;
    int js  = r & 3;
    int j0  = js * 256;

    int tid = threadIdx.x;
    int w = tid >> 6, lane = tid & 63;
    int l15 = lane & 15, lq = lane >> 4;
    int kb = lq * 8;

    // A-frags: 2 sets x 8 -> 32 i-rows, loaded once from global (L2-hot)
    bf16x8 af0[8], af1[8];
    {
        const short* ep = E + ((size_t)b*1024 + i0 + w*32 + l15) * 256 + kb;
        #pragma unroll
        for (int g = 0; g < 8; ++g){
            af0[g] = *(const bf16x8*)(ep + g*32);
            af1[g] = *(const bf16x8*)(ep + 16*256 + g*32);
        }
    }

    // column-bias preload: lane's j per tile jt is j0 + jt*16 + l15
    float cbv[16];
    #pragma unroll
    for (int jt = 0; jt < 16; ++jt)
        cbv[jt] = cb[b*1024 + j0 + jt*16 + l15];

    float ls0[4] = {0.f,0.f,0.f,0.f};
    float ls1[4] = {0.f,0.f,0.f,0.f};
    const short* vp = V + ((size_t)b*1024 + j0 + l15) * 256 + kb;

    #pragma unroll 2
    for (int jt = 0; jt < 16; ++jt){
        const short* vt = vp + (size_t)jt*16*256;
        f32x4 c0 = {0.f,0.f,0.f,0.f};
        f32x4 c1 = {0.f,0.f,0.f,0.f};
        #pragma unroll
        for (int g = 0; g < 8; ++g){
            bf16x8 bf = *(const bf16x8*)(vt + g*32);
            c0 = __builtin_amdgcn_mfma_f32_16x16x32_bf16(af0[g], bf, c0, 0, 0, 0);
            c1 = __builtin_amdgcn_mfma_f32_16x16x32_bf16(af1[g], bf, c1, 0, 0, 0);
        }
        float cbj = cbv[jt];
        #pragma unroll
        for (int q = 0; q < 4; ++q){
            ls0[q] += __expf(fmaf(c0[q], INVT, cbj));
            ls1[q] += __expf(fmaf(c1[q], INVT, cbj));
        }
    }

    // reduce across the 16 lanes sharing each row
    #pragma unroll
    for (int q = 0; q < 4; ++q){
        #pragma unroll
        for (int mm = 1; mm < 16; mm <<= 1){
            ls0[q] += __shfl_xor(ls0[q], mm);
            ls1[q] += __shfl_xor(ls1[q], mm);
        }
    }
    if (l15 == 0){
        float* pp = psum + (((size_t)(b*4 + js)) << 10);
        int ibase = i0 + w*32 + lq*4;
        #pragma unroll
        for (int q = 0; q < 4; ++q){
            pp[ibase + q]      = ls0[q];
            pp[ibase + 16 + q] = ls1[q];
        }
    }
}

// ---- banded positive max: one 16-lane group per row, <=5 candidate cols via idx.
__global__ __launch_bounds__(256) void pos_kernel(const short* __restrict__ E,
                                                  const short* __restrict__ V,
                                                  const int* __restrict__ mask,
                                                  const int* __restrict__ rank,
                                                  const int* __restrict__ idx,
                                                  const int* __restrict__ Tv,
                                                  float* __restrict__ pmax){
    int tid = threadIdx.x;
    int gl  = tid & 15;
    int rf  = (blockIdx.x * 256 + tid) >> 4;   // 0..32767
    int b   = rf >> 10;
    if (mask[rf] <= 0) return;

    int ri = rank[rf];
    int tv = Tv[b];
    int lo = ri - 2; if (lo < 0) lo = 0;
    int hi = ri + 2; if (hi > tv - 1) hi = tv - 1;

    const short* epp = E + (size_t)rf * 256 + gl * 16;
    float ev[16];
    {
        bf16x8 e0 = *(const bf16x8*)epp;
        bf16x8 e1 = *(const bf16x8*)(epp + 8);
        #pragma unroll
        for (int k = 0; k < 8; ++k){ ev[k] = bf2f(e0[k]); ev[8+k] = bf2f(e1[k]); }
    }
    float pm = -1e30f;
    for (int r = lo; r <= hi; ++r){
        int j = idx[b*1024 + r];
        const short* vpp = V + ((size_t)(b*1024) + j) * 256 + gl * 16;
        bf16x8 v0 = *(const bf16x8*)vpp;
        bf16x8 v1 = *(const bf16x8*)(vpp + 8);
        float s = 0.f;
        #pragma unroll
        for (int k = 0; k < 8; ++k){
            s = fmaf(ev[k],   bf2f(v0[k]), s);
            s = fmaf(ev[8+k], bf2f(v1[k]), s);
        }
        s += __shfl_xor(s, 1);
        s += __shfl_xor(s, 2);
        s += __shfl_xor(s, 4);
        s += __shfl_xor(s, 8);
        pm = fmaxf(pm, s);
    }
    if (gl == 0) pmax[rf] = pm * INVT;
}

// ---- partial reduce: 4 blocks per b, each thread one i; coalesced psum reads.
// atomicAdd partial sums into bsum[b] (zeroed by prep).
__global__ __launch_bounds__(256) void reduce_kernel(const float* __restrict__ psum,
                                                     const float* __restrict__ pmax,
                                                     const int* __restrict__ mask,
                                                     float* __restrict__ bsum){
    int b  = blockIdx.x >> 2;
    int i  = (blockIdx.x & 3) * 256 + threadIdx.x;
    int g  = b*1024 + i;
    float a = 0.f;
    if (mask[g] > 0){
        const float* pp = psum + ((size_t)b << 12);
        float ps = pp[i] + pp[i + 1024] + pp[i + 2048] + pp[i + 3072];
        a = logf(ps) - pmax[g];
    }
    #pragma unroll
    for (int m = 1; m < 64; m <<= 1) a += __shfl_xor(a, m);
    if ((threadIdx.x & 63) == 0 && a != 0.f) atomicAdd(&bsum[b], a);
}

// ---- final: out = sum_b (Tv>=2 ? bsum/Tv : 0) / 32
__global__ void final_kernel(const float* __restrict__ bsum,
                             const int* __restrict__ Tv,
                             float* __restrict__ out){
    int tid = threadIdx.x;
    float v = 0.f;
    if (tid < 32){
        int tv = Tv[tid];
        if (tv >= 2) v = bsum[tid] / (float)tv;
    }
    #pragma unroll
    for (int m = 1; m < 64; m <<= 1) v += __shfl_xor(v, m);
    if (tid == 0) out[0] = v / 32.0f;
}

extern "C" void kernel_launch(void* const* d_in, const int* in_sizes, int n_in,
                              void* d_out, int out_size, void* d_ws, size_t ws_size,
                              hipStream_t stream) {
    const float* eeg  = (const float*)d_in[0];
    const float* eye  = (const float*)d_in[1];
    const int*   mask = (const int*)d_in[2];
    const float* Weeg = (const float*)d_in[3];
    const float* Weye = (const float*)d_in[4];
    float* out = (float*)d_out;

    char* ws = (char*)d_ws;
    short* e_bf  = (short*)(ws);                       // 16 MiB
    short* v_bf  = (short*)(ws + 16777216);            // 16 MiB
    short* wbf   = (short*)(ws + 33554432);            // 256 KiB
    int*   rank  = (int*)  (ws + 33816576);            // 128 KiB
    int*   idx   = (int*)  (ws + 33947648);            // 128 KiB
    float* cb    = (float*)(ws + 34078720);            // 128 KiB
    float* psum  = (float*)(ws + 34209792);            // 512 KiB (32 b x 4 slices x 1024 i)
    float* pmax  = (float*)(ws + 34734080);            // 128 KiB
    int*   Tv    = (int*)  (ws + 34865152);            // 128 B
    float* bsum  = (float*)(ws + 34865280);            // 128 B

    prep_kernel<<<544, 256, 0, stream>>>(Weeg, Weye, mask, wbf, rank, idx, Tv, cb, bsum);
    proj_kernel<<<dim3(512, 2), 256, 0, stream>>>(eeg, eye, wbf, e_bf, v_bf);
    loss_kernel<<<1024, 256, 0, stream>>>(e_bf, v_bf, cb, psum);
    pos_kernel<<<2048, 256, 0, stream>>>(e_bf, v_bf, mask, rank, idx, Tv, pmax);
    reduce_kernel<<<128, 256, 0, stream>>>(psum, pmax, mask, bsum);
    final_kernel<<<1, 64, 0, stream>>>(bsum, Tv, out);
}

// Round 9
// 170.994 us; speedup vs baseline: 1.2041x; 1.2041x over previous
//
#include <hip/hip_runtime.h>
#include <hip/hip_bf16.h>

// B=32, T=1024, D=256 fixed by the reference problem.
typedef __attribute__((ext_vector_type(8))) short bf16x8;
typedef __attribute__((ext_vector_type(4))) float f32x4;

#define INVT (1.0f/0.07f)

static __device__ __forceinline__ short f2bf(float f){
    unsigned int u = __float_as_uint(f);
    unsigned int r = (u + 0x7fffu + ((u >> 16) & 1u)) >> 16;
    return (short)r;
}
static __device__ __forceinline__ float bf2f(short s){
    return __uint_as_float(((unsigned int)(unsigned short)s) << 16);
}

// async global->LDS, 16B per lane; LDS dest = wave-uniform base + lane*16
static __device__ __forceinline__ void gld16(const void* g, void* l){
    __builtin_amdgcn_global_load_lds(
        (const __attribute__((address_space(1))) unsigned int*)g,
        (__attribute__((address_space(3))) unsigned int*)l, 16, 0, 0);
}

// ---- prep: blocks 0..511 convert W to bf16; blocks 512..543 per-batch rank scan + zero bsum
__global__ __launch_bounds__(256) void prep_kernel(const float* __restrict__ Weeg,
                                                   const float* __restrict__ Weye,
                                                   const int* __restrict__ mask,
                                                   short* __restrict__ Wout,
                                                   int* __restrict__ rank,
                                                   int* __restrict__ idx,
                                                   int* __restrict__ Tv,
                                                   float* __restrict__ cb,
                                                   float* __restrict__ bsum){
    __shared__ int ssum[256];
    int tid = threadIdx.x;
    if (blockIdx.x < 512){
        int i = blockIdx.x * 256 + tid;
        float v = (i < 65536) ? Weeg[i] : Weye[i - 65536];
        Wout[i] = f2bf(v);
        return;
    }
    int b = blockIdx.x - 512;
    if (tid == 0) bsum[b] = 0.f;
    int local[4]; int s = 0;
    #pragma unroll
    for (int q = 0; q < 4; ++q){
        int t = tid*4 + q;
        local[q] = (mask[b*1024 + t] > 0) ? 1 : 0;
        s += local[q];
    }
    ssum[tid] = s;
    __syncthreads();
    for (int off = 1; off < 256; off <<= 1){
        int add = (tid >= off) ? ssum[tid - off] : 0;
        __syncthreads();
        ssum[tid] += add;
        __syncthreads();
    }
    int run = ssum[tid] - s;
    #pragma unroll
    for (int q = 0; q < 4; ++q){
        int t = tid*4 + q;
        int g = b*1024 + t;
        run += local[q];
        rank[g] = run - 1;
        cb[g]   = local[q] ? 0.0f : -1e9f;
        if (local[q]) idx[b*1024 + run - 1] = t;
    }
    if (tid == 255) Tv[b] = ssum[255];
}

// ---- fused projection + L2 normalize, both modalities (blockIdx.y selects).
// W staged via global_load_lds(16B) into XOR-swizzled unpadded LDS (32 KB).
__global__ __launch_bounds__(256, 5) void proj_kernel(const float* __restrict__ Aeeg,
                                                      const float* __restrict__ Aeye,
                                                      const short* __restrict__ Wbf,
                                                      short* __restrict__ Eout,
                                                      short* __restrict__ Vout){
    __shared__ short sW[64 * 256];     // unpadded; XOR-swizzled in 16B blocks
    int sel = blockIdx.y;
    const float* A   = sel ? Aeye : Aeeg;
    const short* W   = Wbf + sel * 65536;
    short*       Out = sel ? Vout : Eout;

    int tid = threadIdx.x;
    int w = tid >> 6, lane = tid & 63;
    int l15 = lane & 15, lq = lane >> 4;
    int kb  = lq * 8;
    int row0 = blockIdx.x * 64;

    // X-row fragments (B-operand), f32 -> bf16
    bf16x8 xf[8];
    {
        const float* ap = A + (size_t)(row0 + w*16 + l15) * 256 + kb;
        #pragma unroll
        for (int g = 0; g < 8; ++g){
            float4 x0 = *(const float4*)(ap + g*32);
            float4 x1 = *(const float4*)(ap + g*32 + 4);
            bf16x8 t;
            t[0]=f2bf(x0.x); t[1]=f2bf(x0.y); t[2]=f2bf(x0.z); t[3]=f2bf(x0.w);
            t[4]=f2bf(x1.x); t[5]=f2bf(x1.y); t[6]=f2bf(x1.z); t[7]=f2bf(x1.w);
            xf[g] = t;
        }
    }

    f32x4 acc[16];
    #pragma unroll
    for (int q = 0; q < 16; ++q) acc[q] = (f32x4){0.f,0.f,0.f,0.f};

    int ro   = lane >> 5;        // 0..1: row within a 1KB gld16 issue
    int cb_s = lane & 31;        // 16B col-block within a 512B row
    int s7   = l15 & 7;

    #pragma unroll
    for (int pass = 0; pass < 4; ++pass){
        if (pass) __syncthreads();
        // stage W rows [pass*64, +64): each wave 16 rows, 2 rows per issue
        #pragma unroll
        for (int p = 0; p < 8; ++p){
            int rl  = w*16 + p*2 + ro;                 // LDS row index
            int cbg = cb_s ^ ((p*2 + ro) & 7);         // swizzled global col-block
            gld16(W + (size_t)(pass*64 + rl)*256 + cbg*8,
                  &sW[(w*16 + p*2) * 256]);
        }
        __syncthreads();
        #pragma unroll
        for (int nt = 0; nt < 4; ++nt){
            f32x4 c = acc[pass*4 + nt];
            int rbase = (nt*16 + l15) * 256;
            #pragma unroll
            for (int g = 0; g < 8; ++g){
                bf16x8 wf = *(const bf16x8*)&sW[rbase + (((g*4 + lq) ^ s7) << 3)];
                c = __builtin_amdgcn_mfma_f32_16x16x32_bf16(wf, xf[g], c, 0, 0, 0);
            }
            acc[pass*4 + nt] = c;
        }
    }

    // D[e][xrow]: lane holds xrow = l15, e = (pass*4+nt)*16 + lq*4 + r
    float ss = 0.f;
    #pragma unroll
    for (int q = 0; q < 16; ++q){
        #pragma unroll
        for (int r = 0; r < 4; ++r){ float x = acc[q][r]; ss += x*x; }
    }
    ss += __shfl_xor(ss, 16);
    ss += __shfl_xor(ss, 32);
    float scale = 1.0f / fmaxf(sqrtf(ss), 1e-12f);

    short* op = Out + (size_t)(row0 + w*16 + l15) * 256 + lq*4;
    #pragma unroll
    for (int q = 0; q < 16; ++q){
        short4 pk;
        pk.x = f2bf(acc[q][0] * scale);
        pk.y = f2bf(acc[q][1] * scale);
        pk.z = f2bf(acc[q][2] * scale);
        pk.w = f2bf(acc[q][3] * scale);
        *(short4*)(op + ((q >> 2) * 64 + (q & 3) * 16)) = pk;
    }
}

// ---- loss: hybrid GEMM. Block = 128i x 128j; wave = 32 i-rows x all 128 j.
// E A-frags register-resident (loaded once from global, no staging). V staged in
// 2 chunks of 64 j-rows x K=256 (32KB) via gld16 into double-buffered LDS ->
// only TWO barriers per block; chunk1's load drain overlaps chunk0's MFMAs.
// XCD-pinned grid (batch b -> XCD b%8). Epilogue: exp row-sums -> psum[b][jb][i],
// dense stores via per-wave LDS bounce (DS ops are wave-ordered; no barrier).
__global__ __launch_bounds__(256, 2) void loss_kernel(const short* __restrict__ E,
                                                      const short* __restrict__ V,
                                                      const float* __restrict__ cb,
                                                      float* __restrict__ psum){
    __shared__ short sV[2][64 * 256];   // 2 x 32KB, XOR-swizzled in 16B blocks
    __shared__ float sRed[4][32];

    // decode: xcd = n&7; m = n>>3; b = (m>>6)*8 + xcd; lm = m&63; i-blk = lm>>3, jb = lm&7
    int n  = blockIdx.x;
    int m  = n >> 3;
    int b  = ((m >> 6) << 3) | (n & 7);
    int lm = m & 63;
    int i0 = (lm >> 3) * 128;
    int jb = lm & 7;
    int j0 = jb * 128;

    int tid = threadIdx.x;
    int w = tid >> 6, lane = tid & 63;
    int l15 = lane & 15, lq = lane >> 4;
    int kb = lq * 8;
    int s7 = l15 & 7;

    // ---- issue chunk-0 V staging (wave w stages chunk rows [w*16, +16))
    int ro = lane >> 5;             // row parity within a 1KB issue
    int cs = lane & 31;             // stored 16B block index
    const short* Vrow = V + ((size_t)b*1024 + j0 + w*16 + ro) * 256;
    #pragma unroll
    for (int p = 0; p < 8; ++p){
        int rr = (p*2 + ro) & 7;
        gld16(Vrow + (size_t)(p*2)*256 + (size_t)((cs ^ rr) * 8),
              &sV[0][(w*16 + p*2) * 256]);
    }

    // ---- A-frags: 2 sets x 8 -> 32 i-rows, register-resident
    bf16x8 af[2][8];
    {
        const short* ep = E + ((size_t)b*1024 + i0 + w*32 + l15) * 256 + kb;
        #pragma unroll
        for (int g = 0; g < 8; ++g){
            af[0][g] = *(const bf16x8*)(ep + g*32);
            af[1][g] = *(const bf16x8*)(ep + 16*256 + g*32);
        }
    }

    // column-bias per j-tile ct (0..7): j = j0 + ct*16 + l15
    float cbv[8];
    #pragma unroll
    for (int ct = 0; ct < 8; ++ct)
        cbv[ct] = cb[b*1024 + j0 + ct*16 + l15];

    f32x4 acc[2][8];
    #pragma unroll
    for (int s = 0; s < 2; ++s)
        #pragma unroll
        for (int ct = 0; ct < 8; ++ct) acc[s][ct] = (f32x4){0.f,0.f,0.f,0.f};

    __syncthreads();    // publishes chunk 0

    // ---- issue chunk-1 V staging (drains during chunk-0 compute)
    #pragma unroll
    for (int p = 0; p < 8; ++p){
        int rr = (p*2 + ro) & 7;
        gld16(Vrow + (size_t)(64 + p*2)*256 + (size_t)((cs ^ rr) * 8),
              &sV[1][(w*16 + p*2) * 256]);
    }

    // ---- compute chunk 0 (j-tiles 0..3)
    #pragma unroll
    for (int jt = 0; jt < 4; ++jt){
        bf16x8 bf[8];
        #pragma unroll
        for (int g = 0; g < 8; ++g)
            bf[g] = *(const bf16x8*)&sV[0][(jt*16 + l15)*256 + (((g*4 + lq) ^ s7) << 3)];
        #pragma unroll
        for (int g = 0; g < 8; ++g){
            acc[0][jt] = __builtin_amdgcn_mfma_f32_16x16x32_bf16(af[0][g], bf[g], acc[0][jt], 0, 0, 0);
            acc[1][jt] = __builtin_amdgcn_mfma_f32_16x16x32_bf16(af[1][g], bf[g], acc[1][jt], 0, 0, 0);
        }
    }

    __syncthreads();    // publishes chunk 1

    // ---- compute chunk 1 (j-tiles 4..7)
    #pragma unroll
    for (int jt = 0; jt < 4; ++jt){
        bf16x8 bf[8];
        #pragma unroll
        for (int g = 0; g < 8; ++g)
            bf[g] = *(const bf16x8*)&sV[1][(jt*16 + l15)*256 + (((g*4 + lq) ^ s7) << 3)];
        #pragma unroll
        for (int g = 0; g < 8; ++g){
            acc[0][4+jt] = __builtin_amdgcn_mfma_f32_16x16x32_bf16(af[0][g], bf[g], acc[0][4+jt], 0, 0, 0);
            acc[1][4+jt] = __builtin_amdgcn_mfma_f32_16x16x32_bf16(af[1][g], bf[g], acc[1][4+jt], 0, 0, 0);
        }
    }

    // ---- epilogue: ls[s][r] = sum_ct exp(acc*INVT + cb[j]); reduce over 16 lanes
    float ls[2][4];
    #pragma unroll
    for (int s = 0; s < 2; ++s){
        #pragma unroll
        for (int r = 0; r < 4; ++r){
            float acv = 0.f;
            #pragma unroll
            for (int ct = 0; ct < 8; ++ct)
                acv += __expf(fmaf(acc[s][ct][r], INVT, cbv[ct]));
            #pragma unroll
            for (int mm = 1; mm < 16; mm <<= 1)
                acv += __shfl_xor(acv, mm);
            ls[s][r] = acv;
        }
    }
    // dense store via per-wave LDS bounce (row i0 + w*32 + s*16 + lq*4 + r)
    if (l15 == 0){
        #pragma unroll
        for (int s = 0; s < 2; ++s)
            #pragma unroll
            for (int r = 0; r < 4; ++r)
                sRed[w][s*16 + lq*4 + r] = ls[s][r];
    }
    float* pp = psum + (((size_t)(b*8 + jb)) << 10);
    if (lane < 32) pp[i0 + w*32 + lane] = sRed[w][lane];
}

// ---- banded positive max: one 16-lane group per row, <=5 candidate cols via idx.
__global__ __launch_bounds__(256) void pos_kernel(const short* __restrict__ E,
                                                  const short* __restrict__ V,
                                                  const int* __restrict__ mask,
                                                  const int* __restrict__ rank,
                                                  const int* __restrict__ idx,
                                                  const int* __restrict__ Tv,
                                                  float* __restrict__ pmax){
    int tid = threadIdx.x;
    int gl  = tid & 15;
    int rf  = (blockIdx.x * 256 + tid) >> 4;   // 0..32767
    int b   = rf >> 10;
    if (mask[rf] <= 0) return;

    int ri = rank[rf];
    int tv = Tv[b];
    int lo = ri - 2; if (lo < 0) lo = 0;
    int hi = ri + 2; if (hi > tv - 1) hi = tv - 1;

    const short* epp = E + (size_t)rf * 256 + gl * 16;
    float ev[16];
    {
        bf16x8 e0 = *(const bf16x8*)epp;
        bf16x8 e1 = *(const bf16x8*)(epp + 8);
        #pragma unroll
        for (int k = 0; k < 8; ++k){ ev[k] = bf2f(e0[k]); ev[8+k] = bf2f(e1[k]); }
    }
    float pm = -1e30f;
    for (int r = lo; r <= hi; ++r){
        int j = idx[b*1024 + r];
        const short* vpp = V + ((size_t)(b*1024) + j) * 256 + gl * 16;
        bf16x8 v0 = *(const bf16x8*)vpp;
        bf16x8 v1 = *(const bf16x8*)(vpp + 8);
        float s = 0.f;
        #pragma unroll
        for (int k = 0; k < 8; ++k){
            s = fmaf(ev[k],   bf2f(v0[k]), s);
            s = fmaf(ev[8+k], bf2f(v1[k]), s);
        }
        s += __shfl_xor(s, 1);
        s += __shfl_xor(s, 2);
        s += __shfl_xor(s, 4);
        s += __shfl_xor(s, 8);
        pm = fmaxf(pm, s);
    }
    if (gl == 0) pmax[rf] = pm * INVT;
}

// ---- partial reduce: 4 blocks per b, each thread one i; coalesced psum reads.
// atomicAdd partial sums into bsum[b] (zeroed by prep).
__global__ __launch_bounds__(256) void reduce_kernel(const float* __restrict__ psum,
                                                     const float* __restrict__ pmax,
                                                     const int* __restrict__ mask,
                                                     float* __restrict__ bsum){
    int b  = blockIdx.x >> 2;
    int i  = (blockIdx.x & 3) * 256 + threadIdx.x;
    int g  = b*1024 + i;
    float a = 0.f;
    if (mask[g] > 0){
        const float* pp = psum + ((size_t)b << 13);
        float ps = 0.f;
        #pragma unroll
        for (int s = 0; s < 8; ++s) ps += pp[i + (s << 10)];
        a = logf(ps) - pmax[g];
    }
    #pragma unroll
    for (int m = 1; m < 64; m <<= 1) a += __shfl_xor(a, m);
    if ((threadIdx.x & 63) == 0 && a != 0.f) atomicAdd(&bsum[b], a);
}

// ---- final: out = sum_b (Tv>=2 ? bsum/Tv : 0) / 32
__global__ void final_kernel(const float* __restrict__ bsum,
                             const int* __restrict__ Tv,
                             float* __restrict__ out){
    int tid = threadIdx.x;
    float v = 0.f;
    if (tid < 32){
        int tv = Tv[tid];
        if (tv >= 2) v = bsum[tid] / (float)tv;
    }
    #pragma unroll
    for (int m = 1; m < 64; m <<= 1) v += __shfl_xor(v, m);
    if (tid == 0) out[0] = v / 32.0f;
}

extern "C" void kernel_launch(void* const* d_in, const int* in_sizes, int n_in,
                              void* d_out, int out_size, void* d_ws, size_t ws_size,
                              hipStream_t stream) {
    const float* eeg  = (const float*)d_in[0];
    const float* eye  = (const float*)d_in[1];
    const int*   mask = (const int*)d_in[2];
    const float* Weeg = (const float*)d_in[3];
    const float* Weye = (const float*)d_in[4];
    float* out = (float*)d_out;

    char* ws = (char*)d_ws;
    short* e_bf  = (short*)(ws);                       // 16 MiB
    short* v_bf  = (short*)(ws + 16777216);            // 16 MiB
    short* wbf   = (short*)(ws + 33554432);            // 256 KiB
    int*   rank  = (int*)  (ws + 33816576);            // 128 KiB
    int*   idx   = (int*)  (ws + 33947648);            // 128 KiB
    float* cb    = (float*)(ws + 34078720);            // 128 KiB
    float* psum  = (float*)(ws + 34209792);            // 1 MiB (32 b x 8 slices x 1024 i)
    float* pmax  = (float*)(ws + 35258368);            // 128 KiB
    int*   Tv    = (int*)  (ws + 35389440);            // 128 B
    float* bsum  = (float*)(ws + 35389568);            // 128 B

    prep_kernel<<<544, 256, 0, stream>>>(Weeg, Weye, mask, wbf, rank, idx, Tv, cb, bsum);
    proj_kernel<<<dim3(512, 2), 256, 0, stream>>>(eeg, eye, wbf, e_bf, v_bf);
    loss_kernel<<<2048, 256, 0, stream>>>(e_bf, v_bf, cb, psum);
    pos_kernel<<<2048, 256, 0, stream>>>(e_bf, v_bf, mask, rank, idx, Tv, pmax);
    reduce_kernel<<<128, 256, 0, stream>>>(psum, pmax, mask, bsum);
    final_kernel<<<1, 64, 0, stream>>>(bsum, Tv, out);
}

// Round 10
// 168.871 us; speedup vs baseline: 1.2193x; 1.0126x over previous
//
#include <hip/hip_runtime.h>
#include <hip/hip_bf16.h>

// B=32, T=1024, D=256 fixed by the reference problem.
typedef __attribute__((ext_vector_type(8))) short bf16x8;
typedef __attribute__((ext_vector_type(4))) float f32x4;

#define INVT (1.0f/0.07f)

static __device__ __forceinline__ short f2bf(float f){
    unsigned int u = __float_as_uint(f);
    unsigned int r = (u + 0x7fffu + ((u >> 16) & 1u)) >> 16;
    return (short)r;
}
static __device__ __forceinline__ float bf2f(short s){
    return __uint_as_float(((unsigned int)(unsigned short)s) << 16);
}

// async global->LDS, 16B per lane; LDS dest = wave-uniform base + lane*16
static __device__ __forceinline__ void gld16(const void* g, void* l){
    __builtin_amdgcn_global_load_lds(
        (const __attribute__((address_space(1))) unsigned int*)g,
        (__attribute__((address_space(3))) unsigned int*)l, 16, 0, 0);
}

// ---- prep: blocks 0..511 convert W to bf16; blocks 512..543 per-batch rank scan + zero bsum
__global__ __launch_bounds__(256) void prep_kernel(const float* __restrict__ Weeg,
                                                   const float* __restrict__ Weye,
                                                   const int* __restrict__ mask,
                                                   short* __restrict__ Wout,
                                                   int* __restrict__ rank,
                                                   int* __restrict__ idx,
                                                   int* __restrict__ Tv,
                                                   float* __restrict__ cb,
                                                   float* __restrict__ bsum){
    __shared__ int ssum[256];
    int tid = threadIdx.x;
    if (blockIdx.x < 512){
        int i = blockIdx.x * 256 + tid;
        float v = (i < 65536) ? Weeg[i] : Weye[i - 65536];
        Wout[i] = f2bf(v);
        return;
    }
    int b = blockIdx.x - 512;
    if (tid == 0) bsum[b] = 0.f;
    int local[4]; int s = 0;
    #pragma unroll
    for (int q = 0; q < 4; ++q){
        int t = tid*4 + q;
        local[q] = (mask[b*1024 + t] > 0) ? 1 : 0;
        s += local[q];
    }
    ssum[tid] = s;
    __syncthreads();
    for (int off = 1; off < 256; off <<= 1){
        int add = (tid >= off) ? ssum[tid - off] : 0;
        __syncthreads();
        ssum[tid] += add;
        __syncthreads();
    }
    int run = ssum[tid] - s;
    #pragma unroll
    for (int q = 0; q < 4; ++q){
        int t = tid*4 + q;
        int g = b*1024 + t;
        run += local[q];
        rank[g] = run - 1;
        cb[g]   = local[q] ? 0.0f : -1e9f;
        if (local[q]) idx[b*1024 + run - 1] = t;
    }
    if (tid == 255) Tv[b] = ssum[255];
}

// ---- fused projection + L2 normalize, both modalities (blockIdx.y selects).
// Double-buffered W staging (2 x 32KB), 4 chunks of 64 W-rows: 4 barriers,
// drains overlapped by compute (R9-loss structure). Dense epilogue via per-wave
// LDS transpose bounce -> fully coalesced 16B/lane stores.
__global__ __launch_bounds__(256, 2) void proj_kernel(const float* __restrict__ Aeeg,
                                                      const float* __restrict__ Aeye,
                                                      const short* __restrict__ Wbf,
                                                      short* __restrict__ Eout,
                                                      short* __restrict__ Vout){
    __shared__ short sW[2][64 * 256];   // 2 x 32KB, XOR-swizzled in 16B blocks
    int sel = blockIdx.y;
    const float* A   = sel ? Aeye : Aeeg;
    const short* W   = Wbf + sel * 65536;
    short*       Out = sel ? Vout : Eout;

    int tid = threadIdx.x;
    int w = tid >> 6, lane = tid & 63;
    int l15 = lane & 15, lq = lane >> 4;
    int kb  = lq * 8;
    int row0 = blockIdx.x * 64;

    int ro   = lane >> 5;        // 0..1: row within a 1KB gld16 issue
    int cs   = lane & 31;        // 16B col-block within a 512B row
    int s7   = l15 & 7;

    // issue chunk 0 (W rows 0..63) -> buf0  and chunk 1 (64..127) -> buf1
    #pragma unroll
    for (int p = 0; p < 8; ++p){
        int rr = (p*2 + ro) & 7;
        gld16(W + (size_t)(w*16 + p*2 + ro)*256 + (cs ^ rr)*8,
              &sW[0][(w*16 + p*2) * 256]);
    }
    #pragma unroll
    for (int p = 0; p < 8; ++p){
        int rr = (p*2 + ro) & 7;
        gld16(W + (size_t)(64 + w*16 + p*2 + ro)*256 + (cs ^ rr)*8,
              &sW[1][(w*16 + p*2) * 256]);
    }

    // X-row fragments (B-operand), f32 -> bf16 (HBM; drains with chunk0/1)
    bf16x8 xf[8];
    {
        const float* ap = A + (size_t)(row0 + w*16 + l15) * 256 + kb;
        #pragma unroll
        for (int g = 0; g < 8; ++g){
            float4 x0 = *(const float4*)(ap + g*32);
            float4 x1 = *(const float4*)(ap + g*32 + 4);
            bf16x8 t;
            t[0]=f2bf(x0.x); t[1]=f2bf(x0.y); t[2]=f2bf(x0.z); t[3]=f2bf(x0.w);
            t[4]=f2bf(x1.x); t[5]=f2bf(x1.y); t[6]=f2bf(x1.z); t[7]=f2bf(x1.w);
            xf[g] = t;
        }
    }

    f32x4 acc[16];
    #pragma unroll
    for (int q = 0; q < 16; ++q) acc[q] = (f32x4){0.f,0.f,0.f,0.f};

    __syncthreads();   // c0, c1, xf ready

    // compute chunk 0 (e-tiles 0..3) from buf0
    #pragma unroll
    for (int nt = 0; nt < 4; ++nt){
        f32x4 c = acc[nt];
        int rbase = (nt*16 + l15) * 256;
        #pragma unroll
        for (int g = 0; g < 8; ++g){
            bf16x8 wf = *(const bf16x8*)&sW[0][rbase + (((g*4 + lq) ^ s7) << 3)];
            c = __builtin_amdgcn_mfma_f32_16x16x32_bf16(wf, xf[g], c, 0, 0, 0);
        }
        acc[nt] = c;
    }

    __syncthreads();   // all waves done with buf0 (drains nothing new)

    // issue chunk 2 (128..191) -> buf0
    #pragma unroll
    for (int p = 0; p < 8; ++p){
        int rr = (p*2 + ro) & 7;
        gld16(W + (size_t)(128 + w*16 + p*2 + ro)*256 + (cs ^ rr)*8,
              &sW[0][(w*16 + p*2) * 256]);
    }
    // compute chunk 1 (e-tiles 4..7) from buf1
    #pragma unroll
    for (int nt = 0; nt < 4; ++nt){
        f32x4 c = acc[4 + nt];
        int rbase = (nt*16 + l15) * 256;
        #pragma unroll
        for (int g = 0; g < 8; ++g){
            bf16x8 wf = *(const bf16x8*)&sW[1][rbase + (((g*4 + lq) ^ s7) << 3)];
            c = __builtin_amdgcn_mfma_f32_16x16x32_bf16(wf, xf[g], c, 0, 0, 0);
        }
        acc[4 + nt] = c;
    }

    __syncthreads();   // c2 ready (drain overlapped by chunk-1 compute)

    // issue chunk 3 (192..255) -> buf1
    #pragma unroll
    for (int p = 0; p < 8; ++p){
        int rr = (p*2 + ro) & 7;
        gld16(W + (size_t)(192 + w*16 + p*2 + ro)*256 + (cs ^ rr)*8,
              &sW[1][(w*16 + p*2) * 256]);
    }
    // compute chunk 2 (e-tiles 8..11) from buf0
    #pragma unroll
    for (int nt = 0; nt < 4; ++nt){
        f32x4 c = acc[8 + nt];
        int rbase = (nt*16 + l15) * 256;
        #pragma unroll
        for (int g = 0; g < 8; ++g){
            bf16x8 wf = *(const bf16x8*)&sW[0][rbase + (((g*4 + lq) ^ s7) << 3)];
            c = __builtin_amdgcn_mfma_f32_16x16x32_bf16(wf, xf[g], c, 0, 0, 0);
        }
        acc[8 + nt] = c;
    }

    __syncthreads();   // c3 ready (drain overlapped by chunk-2 compute)

    // compute chunk 3 (e-tiles 12..15) from buf1
    #pragma unroll
    for (int nt = 0; nt < 4; ++nt){
        f32x4 c = acc[12 + nt];
        int rbase = (nt*16 + l15) * 256;
        #pragma unroll
        for (int g = 0; g < 8; ++g){
            bf16x8 wf = *(const bf16x8*)&sW[1][rbase + (((g*4 + lq) ^ s7) << 3)];
            c = __builtin_amdgcn_mfma_f32_16x16x32_bf16(wf, xf[g], c, 0, 0, 0);
        }
        acc[12 + nt] = c;
    }

    // D[e][xrow]: lane holds xrow = l15, e = q*16-ish; per-row sum of squares
    float ss = 0.f;
    #pragma unroll
    for (int q = 0; q < 16; ++q){
        #pragma unroll
        for (int r = 0; r < 4; ++r){ float x = acc[q][r]; ss += x*x; }
    }
    ss += __shfl_xor(ss, 16);
    ss += __shfl_xor(ss, 32);
    float scale = 1.0f / fmaxf(sqrtf(ss), 1e-12f);

    // dense epilogue: per-wave transpose bounce through buf0 rows [w*16,+16).
    // Safe without barrier: after the last sync, buf0's readers (chunk-2 compute,
    // which precedes that sync for every wave) are all done; chunk-3 compute
    // reads buf1 only. DS ops within a wave are ordered by lgkmcnt.
    short* tw = &sW[0][(w*16 + l15) * 256 + lq*4];
    #pragma unroll
    for (int q = 0; q < 16; ++q){
        short4 pk;
        pk.x = f2bf(acc[q][0] * scale);
        pk.y = f2bf(acc[q][1] * scale);
        pk.z = f2bf(acc[q][2] * scale);
        pk.w = f2bf(acc[q][3] * scale);
        *(short4*)(tw + ((q >> 2) * 64 + (q & 3) * 16)) = pk;
    }
    const short* tr = &sW[0][(w*16) * 256];
    short* op = Out + (size_t)(row0 + w*16) * 256;
    #pragma unroll
    for (int p = 0; p < 8; ++p){
        int s = p*512 + lane*8;
        *(int4*)(op + s) = *(const int4*)(tr + s);
    }
}

// ---- loss: hybrid GEMM. Block = 128i x 128j; wave = 32 i-rows x all 128 j.
// E A-frags register-resident. V staged in 2 chunks of 64 j-rows x K=256 (32KB)
// via gld16 into double-buffered LDS -> two barriers; chunk1 drain overlapped.
// XCD-pinned grid. Epilogue: exp row-sums -> psum[b][jb][i], dense stores.
__global__ __launch_bounds__(256, 2) void loss_kernel(const short* __restrict__ E,
                                                      const short* __restrict__ V,
                                                      const float* __restrict__ cb,
                                                      float* __restrict__ psum){
    __shared__ short sV[2][64 * 256];   // 2 x 32KB, XOR-swizzled in 16B blocks
    __shared__ float sRed[4][32];

    int n  = blockIdx.x;
    int m  = n >> 3;
    int b  = ((m >> 6) << 3) | (n & 7);
    int lm = m & 63;
    int i0 = (lm >> 3) * 128;
    int jb = lm & 7;
    int j0 = jb * 128;

    int tid = threadIdx.x;
    int w = tid >> 6, lane = tid & 63;
    int l15 = lane & 15, lq = lane >> 4;
    int kb = lq * 8;
    int s7 = l15 & 7;

    int ro = lane >> 5;
    int cs = lane & 31;
    const short* Vrow = V + ((size_t)b*1024 + j0 + w*16 + ro) * 256;
    #pragma unroll
    for (int p = 0; p < 8; ++p){
        int rr = (p*2 + ro) & 7;
        gld16(Vrow + (size_t)(p*2)*256 + (size_t)((cs ^ rr) * 8),
              &sV[0][(w*16 + p*2) * 256]);
    }

    bf16x8 af[2][8];
    {
        const short* ep = E + ((size_t)b*1024 + i0 + w*32 + l15) * 256 + kb;
        #pragma unroll
        for (int g = 0; g < 8; ++g){
            af[0][g] = *(const bf16x8*)(ep + g*32);
            af[1][g] = *(const bf16x8*)(ep + 16*256 + g*32);
        }
    }

    float cbv[8];
    #pragma unroll
    for (int ct = 0; ct < 8; ++ct)
        cbv[ct] = cb[b*1024 + j0 + ct*16 + l15];

    f32x4 acc[2][8];
    #pragma unroll
    for (int s = 0; s < 2; ++s)
        #pragma unroll
        for (int ct = 0; ct < 8; ++ct) acc[s][ct] = (f32x4){0.f,0.f,0.f,0.f};

    __syncthreads();    // publishes chunk 0

    #pragma unroll
    for (int p = 0; p < 8; ++p){
        int rr = (p*2 + ro) & 7;
        gld16(Vrow + (size_t)(64 + p*2)*256 + (size_t)((cs ^ rr) * 8),
              &sV[1][(w*16 + p*2) * 256]);
    }

    #pragma unroll
    for (int jt = 0; jt < 4; ++jt){
        bf16x8 bf[8];
        #pragma unroll
        for (int g = 0; g < 8; ++g)
            bf[g] = *(const bf16x8*)&sV[0][(jt*16 + l15)*256 + (((g*4 + lq) ^ s7) << 3)];
        #pragma unroll
        for (int g = 0; g < 8; ++g){
            acc[0][jt] = __builtin_amdgcn_mfma_f32_16x16x32_bf16(af[0][g], bf[g], acc[0][jt], 0, 0, 0);
            acc[1][jt] = __builtin_amdgcn_mfma_f32_16x16x32_bf16(af[1][g], bf[g], acc[1][jt], 0, 0, 0);
        }
    }

    __syncthreads();    // publishes chunk 1 (drain overlapped by chunk-0 compute)

    #pragma unroll
    for (int jt = 0; jt < 4; ++jt){
        bf16x8 bf[8];
        #pragma unroll
        for (int g = 0; g < 8; ++g)
            bf[g] = *(const bf16x8*)&sV[1][(jt*16 + l15)*256 + (((g*4 + lq) ^ s7) << 3)];
        #pragma unroll
        for (int g = 0; g < 8; ++g){
            acc[0][4+jt] = __builtin_amdgcn_mfma_f32_16x16x32_bf16(af[0][g], bf[g], acc[0][4+jt], 0, 0, 0);
            acc[1][4+jt] = __builtin_amdgcn_mfma_f32_16x16x32_bf16(af[1][g], bf[g], acc[1][4+jt], 0, 0, 0);
        }
    }

    float ls[2][4];
    #pragma unroll
    for (int s = 0; s < 2; ++s){
        #pragma unroll
        for (int r = 0; r < 4; ++r){
            float acv = 0.f;
            #pragma unroll
            for (int ct = 0; ct < 8; ++ct)
                acv += __expf(fmaf(acc[s][ct][r], INVT, cbv[ct]));
            #pragma unroll
            for (int mm = 1; mm < 16; mm <<= 1)
                acv += __shfl_xor(acv, mm);
            ls[s][r] = acv;
        }
    }
    if (l15 == 0){
        #pragma unroll
        for (int s = 0; s < 2; ++s)
            #pragma unroll
            for (int r = 0; r < 4; ++r)
                sRed[w][s*16 + lq*4 + r] = ls[s][r];
    }
    float* pp = psum + (((size_t)(b*8 + jb)) << 10);
    if (lane < 32) pp[i0 + w*32 + lane] = sRed[w][lane];
}

// ---- banded positive max: one 16-lane group per row, <=5 candidate cols via idx.
__global__ __launch_bounds__(256) void pos_kernel(const short* __restrict__ E,
                                                  const short* __restrict__ V,
                                                  const int* __restrict__ mask,
                                                  const int* __restrict__ rank,
                                                  const int* __restrict__ idx,
                                                  const int* __restrict__ Tv,
                                                  float* __restrict__ pmax){
    int tid = threadIdx.x;
    int gl  = tid & 15;
    int rf  = (blockIdx.x * 256 + tid) >> 4;   // 0..32767
    int b   = rf >> 10;
    if (mask[rf] <= 0) return;

    int ri = rank[rf];
    int tv = Tv[b];
    int lo = ri - 2; if (lo < 0) lo = 0;
    int hi = ri + 2; if (hi > tv - 1) hi = tv - 1;

    const short* epp = E + (size_t)rf * 256 + gl * 16;
    float ev[16];
    {
        bf16x8 e0 = *(const bf16x8*)epp;
        bf16x8 e1 = *(const bf16x8*)(epp + 8);
        #pragma unroll
        for (int k = 0; k < 8; ++k){ ev[k] = bf2f(e0[k]); ev[8+k] = bf2f(e1[k]); }
    }
    float pm = -1e30f;
    for (int r = lo; r <= hi; ++r){
        int j = idx[b*1024 + r];
        const short* vpp = V + ((size_t)(b*1024) + j) * 256 + gl * 16;
        bf16x8 v0 = *(const bf16x8*)vpp;
        bf16x8 v1 = *(const bf16x8*)(vpp + 8);
        float s = 0.f;
        #pragma unroll
        for (int k = 0; k < 8; ++k){
            s = fmaf(ev[k],   bf2f(v0[k]), s);
            s = fmaf(ev[8+k], bf2f(v1[k]), s);
        }
        s += __shfl_xor(s, 1);
        s += __shfl_xor(s, 2);
        s += __shfl_xor(s, 4);
        s += __shfl_xor(s, 8);
        pm = fmaxf(pm, s);
    }
    if (gl == 0) pmax[rf] = pm * INVT;
}

// ---- partial reduce: 4 blocks per b, each thread one i; coalesced psum reads.
__global__ __launch_bounds__(256) void reduce_kernel(const float* __restrict__ psum,
                                                     const float* __restrict__ pmax,
                                                     const int* __restrict__ mask,
                                                     float* __restrict__ bsum){
    int b  = blockIdx.x >> 2;
    int i  = (blockIdx.x & 3) * 256 + threadIdx.x;
    int g  = b*1024 + i;
    float a = 0.f;
    if (mask[g] > 0){
        const float* pp = psum + ((size_t)b << 13);
        float ps = 0.f;
        #pragma unroll
        for (int s = 0; s < 8; ++s) ps += pp[i + (s << 10)];
        a = logf(ps) - pmax[g];
    }
    #pragma unroll
    for (int m = 1; m < 64; m <<= 1) a += __shfl_xor(a, m);
    if ((threadIdx.x & 63) == 0 && a != 0.f) atomicAdd(&bsum[b], a);
}

// ---- final: out = sum_b (Tv>=2 ? bsum/Tv : 0) / 32
__global__ void final_kernel(const float* __restrict__ bsum,
                             const int* __restrict__ Tv,
                             float* __restrict__ out){
    int tid = threadIdx.x;
    float v = 0.f;
    if (tid < 32){
        int tv = Tv[tid];
        if (tv >= 2) v = bsum[tid] / (float)tv;
    }
    #pragma unroll
    for (int m = 1; m < 64; m <<= 1) v += __shfl_xor(v, m);
    if (tid == 0) out[0] = v / 32.0f;
}

extern "C" void kernel_launch(void* const* d_in, const int* in_sizes, int n_in,
                              void* d_out, int out_size, void* d_ws, size_t ws_size,
                              hipStream_t stream) {
    const float* eeg  = (const float*)d_in[0];
    const float* eye  = (const float*)d_in[1];
    const int*   mask = (const int*)d_in[2];
    const float* Weeg = (const float*)d_in[3];
    const float* Weye = (const float*)d_in[4];
    float* out = (float*)d_out;

    char* ws = (char*)d_ws;
    short* e_bf  = (short*)(ws);                       // 16 MiB
    short* v_bf  = (short*)(ws + 16777216);            // 16 MiB
    short* wbf   = (short*)(ws + 33554432);            // 256 KiB
    int*   rank  = (int*)  (ws + 33816576);            // 128 KiB
    int*   idx   = (int*)  (ws + 33947648);            // 128 KiB
    float* cb    = (float*)(ws + 34078720);            // 128 KiB
    float* psum  = (float*)(ws + 34209792);            // 1 MiB (32 b x 8 slices x 1024 i)
    float* pmax  = (float*)(ws + 35258368);            // 128 KiB
    int*   Tv    = (int*)  (ws + 35389440);            // 128 B
    float* bsum  = (float*)(ws + 35389568);            // 128 B

    prep_kernel<<<544, 256, 0, stream>>>(Weeg, Weye, mask, wbf, rank, idx, Tv, cb, bsum);
    proj_kernel<<<dim3(512, 2), 256, 0, stream>>>(eeg, eye, wbf, e_bf, v_bf);
    loss_kernel<<<2048, 256, 0, stream>>>(e_bf, v_bf, cb, psum);
    pos_kernel<<<2048, 256, 0, stream>>>(e_bf, v_bf, mask, rank, idx, Tv, pmax);
    reduce_kernel<<<128, 256, 0, stream>>>(psum, pmax, mask, bsum);
    final_kernel<<<1, 64, 0, stream>>>(bsum, Tv, out);
}

// Round 11
// 163.886 us; speedup vs baseline: 1.2564x; 1.0304x over previous
//
#include <hip/hip_runtime.h>
#include <hip/hip_bf16.h>

// B=32, T=1024, D=256 fixed by the reference problem.
typedef __attribute__((ext_vector_type(8))) short bf16x8;
typedef __attribute__((ext_vector_type(4))) float f32x4;

#define INVT (1.0f/0.07f)

static __device__ __forceinline__ short f2bf(float f){
    unsigned int u = __float_as_uint(f);
    unsigned int r = (u + 0x7fffu + ((u >> 16) & 1u)) >> 16;
    return (short)r;
}
static __device__ __forceinline__ float bf2f(short s){
    return __uint_as_float(((unsigned int)(unsigned short)s) << 16);
}

// async global->LDS, 16B per lane; LDS dest = wave-uniform base + lane*16
static __device__ __forceinline__ void gld16(const void* g, void* l){
    __builtin_amdgcn_global_load_lds(
        (const __attribute__((address_space(1))) unsigned int*)g,
        (__attribute__((address_space(3))) unsigned int*)l, 16, 0, 0);
}

// ---- prep: blocks 0..511 convert W to bf16; blocks 512..543 per-batch rank scan + zero bsum
__global__ __launch_bounds__(256) void prep_kernel(const float* __restrict__ Weeg,
                                                   const float* __restrict__ Weye,
                                                   const int* __restrict__ mask,
                                                   short* __restrict__ Wout,
                                                   int* __restrict__ rank,
                                                   int* __restrict__ idx,
                                                   int* __restrict__ Tv,
                                                   float* __restrict__ cb,
                                                   float* __restrict__ bsum){
    __shared__ int ssum[256];
    int tid = threadIdx.x;
    if (blockIdx.x < 512){
        int i = blockIdx.x * 256 + tid;
        float v = (i < 65536) ? Weeg[i] : Weye[i - 65536];
        Wout[i] = f2bf(v);
        return;
    }
    int b = blockIdx.x - 512;
    if (tid == 0) bsum[b] = 0.f;
    int local[4]; int s = 0;
    #pragma unroll
    for (int q = 0; q < 4; ++q){
        int t = tid*4 + q;
        local[q] = (mask[b*1024 + t] > 0) ? 1 : 0;
        s += local[q];
    }
    ssum[tid] = s;
    __syncthreads();
    for (int off = 1; off < 256; off <<= 1){
        int add = (tid >= off) ? ssum[tid - off] : 0;
        __syncthreads();
        ssum[tid] += add;
        __syncthreads();
    }
    int run = ssum[tid] - s;
    #pragma unroll
    for (int q = 0; q < 4; ++q){
        int t = tid*4 + q;
        int g = b*1024 + t;
        run += local[q];
        rank[g] = run - 1;
        cb[g]   = local[q] ? 0.0f : -1e9f;
        if (local[q]) idx[b*1024 + run - 1] = t;
    }
    if (tid == 255) Tv[b] = ssum[255];
}

// ---- fused projection + L2 normalize, both modalities (blockIdx.y selects).
// Double-buffered W staging (2 x 32KB), 4 chunks of 64 W-rows, drains overlapped.
// Dense epilogue via per-wave LDS transpose bounce -> coalesced 16B/lane stores.
__global__ __launch_bounds__(256, 2) void proj_kernel(const float* __restrict__ Aeeg,
                                                      const float* __restrict__ Aeye,
                                                      const short* __restrict__ Wbf,
                                                      short* __restrict__ Eout,
                                                      short* __restrict__ Vout){
    __shared__ short sW[2][64 * 256];   // 2 x 32KB, XOR-swizzled in 16B blocks
    int sel = blockIdx.y;
    const float* A   = sel ? Aeye : Aeeg;
    const short* W   = Wbf + sel * 65536;
    short*       Out = sel ? Vout : Eout;

    int tid = threadIdx.x;
    int w = tid >> 6, lane = tid & 63;
    int l15 = lane & 15, lq = lane >> 4;
    int kb  = lq * 8;
    int row0 = blockIdx.x * 64;

    int ro   = lane >> 5;
    int cs   = lane & 31;
    int s7   = l15 & 7;

    // issue chunk 0 (W rows 0..63) -> buf0 and chunk 1 (64..127) -> buf1
    #pragma unroll
    for (int p = 0; p < 8; ++p){
        int rr = (p*2 + ro) & 7;
        gld16(W + (size_t)(w*16 + p*2 + ro)*256 + (cs ^ rr)*8,
              &sW[0][(w*16 + p*2) * 256]);
    }
    #pragma unroll
    for (int p = 0; p < 8; ++p){
        int rr = (p*2 + ro) & 7;
        gld16(W + (size_t)(64 + w*16 + p*2 + ro)*256 + (cs ^ rr)*8,
              &sW[1][(w*16 + p*2) * 256]);
    }

    // X-row fragments (B-operand), f32 -> bf16 (HBM; drains with chunk0/1)
    bf16x8 xf[8];
    {
        const float* ap = A + (size_t)(row0 + w*16 + l15) * 256 + kb;
        #pragma unroll
        for (int g = 0; g < 8; ++g){
            float4 x0 = *(const float4*)(ap + g*32);
            float4 x1 = *(const float4*)(ap + g*32 + 4);
            bf16x8 t;
            t[0]=f2bf(x0.x); t[1]=f2bf(x0.y); t[2]=f2bf(x0.z); t[3]=f2bf(x0.w);
            t[4]=f2bf(x1.x); t[5]=f2bf(x1.y); t[6]=f2bf(x1.z); t[7]=f2bf(x1.w);
            xf[g] = t;
        }
    }

    f32x4 acc[16];
    #pragma unroll
    for (int q = 0; q < 16; ++q) acc[q] = (f32x4){0.f,0.f,0.f,0.f};

    __syncthreads();   // c0, c1, xf ready

    #pragma unroll
    for (int nt = 0; nt < 4; ++nt){
        f32x4 c = acc[nt];
        int rbase = (nt*16 + l15) * 256;
        #pragma unroll
        for (int g = 0; g < 8; ++g){
            bf16x8 wf = *(const bf16x8*)&sW[0][rbase + (((g*4 + lq) ^ s7) << 3)];
            c = __builtin_amdgcn_mfma_f32_16x16x32_bf16(wf, xf[g], c, 0, 0, 0);
        }
        acc[nt] = c;
    }

    __syncthreads();

    #pragma unroll
    for (int p = 0; p < 8; ++p){
        int rr = (p*2 + ro) & 7;
        gld16(W + (size_t)(128 + w*16 + p*2 + ro)*256 + (cs ^ rr)*8,
              &sW[0][(w*16 + p*2) * 256]);
    }
    #pragma unroll
    for (int nt = 0; nt < 4; ++nt){
        f32x4 c = acc[4 + nt];
        int rbase = (nt*16 + l15) * 256;
        #pragma unroll
        for (int g = 0; g < 8; ++g){
            bf16x8 wf = *(const bf16x8*)&sW[1][rbase + (((g*4 + lq) ^ s7) << 3)];
            c = __builtin_amdgcn_mfma_f32_16x16x32_bf16(wf, xf[g], c, 0, 0, 0);
        }
        acc[4 + nt] = c;
    }

    __syncthreads();

    #pragma unroll
    for (int p = 0; p < 8; ++p){
        int rr = (p*2 + ro) & 7;
        gld16(W + (size_t)(192 + w*16 + p*2 + ro)*256 + (cs ^ rr)*8,
              &sW[1][(w*16 + p*2) * 256]);
    }
    #pragma unroll
    for (int nt = 0; nt < 4; ++nt){
        f32x4 c = acc[8 + nt];
        int rbase = (nt*16 + l15) * 256;
        #pragma unroll
        for (int g = 0; g < 8; ++g){
            bf16x8 wf = *(const bf16x8*)&sW[0][rbase + (((g*4 + lq) ^ s7) << 3)];
            c = __builtin_amdgcn_mfma_f32_16x16x32_bf16(wf, xf[g], c, 0, 0, 0);
        }
        acc[8 + nt] = c;
    }

    __syncthreads();

    #pragma unroll
    for (int nt = 0; nt < 4; ++nt){
        f32x4 c = acc[12 + nt];
        int rbase = (nt*16 + l15) * 256;
        #pragma unroll
        for (int g = 0; g < 8; ++g){
            bf16x8 wf = *(const bf16x8*)&sW[1][rbase + (((g*4 + lq) ^ s7) << 3)];
            c = __builtin_amdgcn_mfma_f32_16x16x32_bf16(wf, xf[g], c, 0, 0, 0);
        }
        acc[12 + nt] = c;
    }

    float ss = 0.f;
    #pragma unroll
    for (int q = 0; q < 16; ++q){
        #pragma unroll
        for (int r = 0; r < 4; ++r){ float x = acc[q][r]; ss += x*x; }
    }
    ss += __shfl_xor(ss, 16);
    ss += __shfl_xor(ss, 32);
    float scale = 1.0f / fmaxf(sqrtf(ss), 1e-12f);

    // dense epilogue via per-wave transpose bounce through buf0 rows [w*16,+16)
    short* tw = &sW[0][(w*16 + l15) * 256 + lq*4];
    #pragma unroll
    for (int q = 0; q < 16; ++q){
        short4 pk;
        pk.x = f2bf(acc[q][0] * scale);
        pk.y = f2bf(acc[q][1] * scale);
        pk.z = f2bf(acc[q][2] * scale);
        pk.w = f2bf(acc[q][3] * scale);
        *(short4*)(tw + ((q >> 2) * 64 + (q & 3) * 16)) = pk;
    }
    const short* tr = &sW[0][(w*16) * 256];
    short* op = Out + (size_t)(row0 + w*16) * 256;
    #pragma unroll
    for (int p = 0; p < 8; ++p){
        int s = p*512 + lane*8;
        *(int4*)(op + s) = *(const int4*)(tr + s);
    }
}

// ---- loss: block = 128i x 256j; wave = 32 i-rows. E A-frags loaded ONCE per
// 256-j sweep. V staged in 4 chunks of 64 j-rows x K=256 (32KB) through a
// 2x32KB double buffer; 4 barriers, drains overlapped (R10-proj pipeline).
// exp row-sum is additive across j -> acc registers reused per 128-j half.
// XCD-pinned grid 1024. Epilogue -> psum[b][js][i] (4 slices), dense stores.
__global__ __launch_bounds__(256, 2) void loss_kernel(const short* __restrict__ E,
                                                      const short* __restrict__ V,
                                                      const float* __restrict__ cb,
                                                      float* __restrict__ psum){
    __shared__ short sV[2][64 * 256];   // 2 x 32KB, XOR-swizzled in 16B blocks
    __shared__ float sRed[4][32];

    // decode: xcd = n&7; m = n>>3 (0..127); b = (m>>5)*8 + xcd; lm = m&31
    int n  = blockIdx.x;
    int m  = n >> 3;
    int b  = ((m >> 5) << 3) | (n & 7);
    int lm = m & 31;
    int i0 = (lm >> 2) * 128;
    int js = lm & 3;
    int j0 = js * 256;

    int tid = threadIdx.x;
    int w = tid >> 6, lane = tid & 63;
    int l15 = lane & 15, lq = lane >> 4;
    int kb = lq * 8;
    int s7 = l15 & 7;
    int ro = lane >> 5;
    int cs = lane & 31;

    const short* Vrow = V + ((size_t)b*1024 + j0 + w*16 + ro) * 256;

    // issue h0c0 (j rows 0..63) -> buf0
    #pragma unroll
    for (int p = 0; p < 8; ++p){
        int rr = (p*2 + ro) & 7;
        gld16(Vrow + (size_t)(p*2)*256 + (size_t)((cs ^ rr) * 8),
              &sV[0][(w*16 + p*2) * 256]);
    }

    // A-frags: 2 sets x 8 -> 32 i-rows, register-resident, loaded once
    bf16x8 af[2][8];
    {
        const short* ep = E + ((size_t)b*1024 + i0 + w*32 + l15) * 256 + kb;
        #pragma unroll
        for (int g = 0; g < 8; ++g){
            af[0][g] = *(const bf16x8*)(ep + g*32);
            af[1][g] = *(const bf16x8*)(ep + 16*256 + g*32);
        }
    }

    float cbv0[8];
    #pragma unroll
    for (int ct = 0; ct < 8; ++ct)
        cbv0[ct] = cb[b*1024 + j0 + ct*16 + l15];

    f32x4 acc[2][8];
    #pragma unroll
    for (int s = 0; s < 2; ++s)
        #pragma unroll
        for (int ct = 0; ct < 8; ++ct) acc[s][ct] = (f32x4){0.f,0.f,0.f,0.f};
    float ls[2][4] = {{0.f,0.f,0.f,0.f},{0.f,0.f,0.f,0.f}};

    __syncthreads();    // publish h0c0

    // issue h0c1 (64..127) -> buf1
    #pragma unroll
    for (int p = 0; p < 8; ++p){
        int rr = (p*2 + ro) & 7;
        gld16(Vrow + (size_t)(64 + p*2)*256 + (size_t)((cs ^ rr) * 8),
              &sV[1][(w*16 + p*2) * 256]);
    }
    // compute h0c0 from buf0
    #pragma unroll
    for (int jt = 0; jt < 4; ++jt){
        bf16x8 bf[8];
        #pragma unroll
        for (int g = 0; g < 8; ++g)
            bf[g] = *(const bf16x8*)&sV[0][(jt*16 + l15)*256 + (((g*4 + lq) ^ s7) << 3)];
        #pragma unroll
        for (int g = 0; g < 8; ++g){
            acc[0][jt] = __builtin_amdgcn_mfma_f32_16x16x32_bf16(af[0][g], bf[g], acc[0][jt], 0, 0, 0);
            acc[1][jt] = __builtin_amdgcn_mfma_f32_16x16x32_bf16(af[1][g], bf[g], acc[1][jt], 0, 0, 0);
        }
    }

    __syncthreads();    // publish h0c1 (drain overlapped by h0c0 compute)

    // issue h1c0 (128..191) -> buf0
    #pragma unroll
    for (int p = 0; p < 8; ++p){
        int rr = (p*2 + ro) & 7;
        gld16(Vrow + (size_t)(128 + p*2)*256 + (size_t)((cs ^ rr) * 8),
              &sV[0][(w*16 + p*2) * 256]);
    }
    // compute h0c1 from buf1
    #pragma unroll
    for (int jt = 0; jt < 4; ++jt){
        bf16x8 bf[8];
        #pragma unroll
        for (int g = 0; g < 8; ++g)
            bf[g] = *(const bf16x8*)&sV[1][(jt*16 + l15)*256 + (((g*4 + lq) ^ s7) << 3)];
        #pragma unroll
        for (int g = 0; g < 8; ++g){
            acc[0][4+jt] = __builtin_amdgcn_mfma_f32_16x16x32_bf16(af[0][g], bf[g], acc[0][4+jt], 0, 0, 0);
            acc[1][4+jt] = __builtin_amdgcn_mfma_f32_16x16x32_bf16(af[1][g], bf[g], acc[1][4+jt], 0, 0, 0);
        }
    }
    // epilogue-accumulate half0 (overlaps h1c0 drain), then reset acc
    #pragma unroll
    for (int s = 0; s < 2; ++s){
        #pragma unroll
        for (int r = 0; r < 4; ++r){
            float a0 = 0.f;
            #pragma unroll
            for (int ct = 0; ct < 8; ++ct)
                a0 += __expf(fmaf(acc[s][ct][r], INVT, cbv0[ct]));
            ls[s][r] += a0;
        }
    }
    #pragma unroll
    for (int s = 0; s < 2; ++s)
        #pragma unroll
        for (int ct = 0; ct < 8; ++ct) acc[s][ct] = (f32x4){0.f,0.f,0.f,0.f};

    float cbv1[8];
    #pragma unroll
    for (int ct = 0; ct < 8; ++ct)
        cbv1[ct] = cb[b*1024 + j0 + 128 + ct*16 + l15];

    __syncthreads();    // publish h1c0

    // issue h1c1 (192..255) -> buf1
    #pragma unroll
    for (int p = 0; p < 8; ++p){
        int rr = (p*2 + ro) & 7;
        gld16(Vrow + (size_t)(192 + p*2)*256 + (size_t)((cs ^ rr) * 8),
              &sV[1][(w*16 + p*2) * 256]);
    }
    // compute h1c0 from buf0
    #pragma unroll
    for (int jt = 0; jt < 4; ++jt){
        bf16x8 bf[8];
        #pragma unroll
        for (int g = 0; g < 8; ++g)
            bf[g] = *(const bf16x8*)&sV[0][(jt*16 + l15)*256 + (((g*4 + lq) ^ s7) << 3)];
        #pragma unroll
        for (int g = 0; g < 8; ++g){
            acc[0][jt] = __builtin_amdgcn_mfma_f32_16x16x32_bf16(af[0][g], bf[g], acc[0][jt], 0, 0, 0);
            acc[1][jt] = __builtin_amdgcn_mfma_f32_16x16x32_bf16(af[1][g], bf[g], acc[1][jt], 0, 0, 0);
        }
    }

    __syncthreads();    // publish h1c1 (drain overlapped by h1c0 compute)

    // compute h1c1 from buf1
    #pragma unroll
    for (int jt = 0; jt < 4; ++jt){
        bf16x8 bf[8];
        #pragma unroll
        for (int g = 0; g < 8; ++g)
            bf[g] = *(const bf16x8*)&sV[1][(jt*16 + l15)*256 + (((g*4 + lq) ^ s7) << 3)];
        #pragma unroll
        for (int g = 0; g < 8; ++g){
            acc[0][4+jt] = __builtin_amdgcn_mfma_f32_16x16x32_bf16(af[0][g], bf[g], acc[0][4+jt], 0, 0, 0);
            acc[1][4+jt] = __builtin_amdgcn_mfma_f32_16x16x32_bf16(af[1][g], bf[g], acc[1][4+jt], 0, 0, 0);
        }
    }
    // epilogue-accumulate half1
    #pragma unroll
    for (int s = 0; s < 2; ++s){
        #pragma unroll
        for (int r = 0; r < 4; ++r){
            float a1 = 0.f;
            #pragma unroll
            for (int ct = 0; ct < 8; ++ct)
                a1 += __expf(fmaf(acc[s][ct][r], INVT, cbv1[ct]));
            ls[s][r] += a1;
        }
    }

    // reduce over the 16 lanes sharing each row; dense store via LDS bounce
    #pragma unroll
    for (int s = 0; s < 2; ++s){
        #pragma unroll
        for (int r = 0; r < 4; ++r){
            float v = ls[s][r];
            #pragma unroll
            for (int mm = 1; mm < 16; mm <<= 1)
                v += __shfl_xor(v, mm);
            ls[s][r] = v;
        }
    }
    if (l15 == 0){
        #pragma unroll
        for (int s = 0; s < 2; ++s)
            #pragma unroll
            for (int r = 0; r < 4; ++r)
                sRed[w][s*16 + lq*4 + r] = ls[s][r];
    }
    float* pp = psum + (((size_t)(b*4 + js)) << 10);
    if (lane < 32) pp[i0 + w*32 + lane] = sRed[w][lane];
}

// ---- banded positive max: one 16-lane group per row, <=5 candidate cols via idx.
__global__ __launch_bounds__(256) void pos_kernel(const short* __restrict__ E,
                                                  const short* __restrict__ V,
                                                  const int* __restrict__ mask,
                                                  const int* __restrict__ rank,
                                                  const int* __restrict__ idx,
                                                  const int* __restrict__ Tv,
                                                  float* __restrict__ pmax){
    int tid = threadIdx.x;
    int gl  = tid & 15;
    int rf  = (blockIdx.x * 256 + tid) >> 4;   // 0..32767
    int b   = rf >> 10;
    if (mask[rf] <= 0) return;

    int ri = rank[rf];
    int tv = Tv[b];
    int lo = ri - 2; if (lo < 0) lo = 0;
    int hi = ri + 2; if (hi > tv - 1) hi = tv - 1;

    const short* epp = E + (size_t)rf * 256 + gl * 16;
    float ev[16];
    {
        bf16x8 e0 = *(const bf16x8*)epp;
        bf16x8 e1 = *(const bf16x8*)(epp + 8);
        #pragma unroll
        for (int k = 0; k < 8; ++k){ ev[k] = bf2f(e0[k]); ev[8+k] = bf2f(e1[k]); }
    }
    float pm = -1e30f;
    for (int r = lo; r <= hi; ++r){
        int j = idx[b*1024 + r];
        const short* vpp = V + ((size_t)(b*1024) + j) * 256 + gl * 16;
        bf16x8 v0 = *(const bf16x8*)vpp;
        bf16x8 v1 = *(const bf16x8*)(vpp + 8);
        float s = 0.f;
        #pragma unroll
        for (int k = 0; k < 8; ++k){
            s = fmaf(ev[k],   bf2f(v0[k]), s);
            s = fmaf(ev[8+k], bf2f(v1[k]), s);
        }
        s += __shfl_xor(s, 1);
        s += __shfl_xor(s, 2);
        s += __shfl_xor(s, 4);
        s += __shfl_xor(s, 8);
        pm = fmaxf(pm, s);
    }
    if (gl == 0) pmax[rf] = pm * INVT;
}

// ---- partial reduce: 4 blocks per b, each thread one i; coalesced psum reads.
__global__ __launch_bounds__(256) void reduce_kernel(const float* __restrict__ psum,
                                                     const float* __restrict__ pmax,
                                                     const int* __restrict__ mask,
                                                     float* __restrict__ bsum){
    int b  = blockIdx.x >> 2;
    int i  = (blockIdx.x & 3) * 256 + threadIdx.x;
    int g  = b*1024 + i;
    float a = 0.f;
    if (mask[g] > 0){
        const float* pp = psum + ((size_t)b << 12);
        float ps = pp[i] + pp[i + 1024] + pp[i + 2048] + pp[i + 3072];
        a = logf(ps) - pmax[g];
    }
    #pragma unroll
    for (int m = 1; m < 64; m <<= 1) a += __shfl_xor(a, m);
    if ((threadIdx.x & 63) == 0 && a != 0.f) atomicAdd(&bsum[b], a);
}

// ---- final: out = sum_b (Tv>=2 ? bsum/Tv : 0) / 32
__global__ void final_kernel(const float* __restrict__ bsum,
                             const int* __restrict__ Tv,
                             float* __restrict__ out){
    int tid = threadIdx.x;
    float v = 0.f;
    if (tid < 32){
        int tv = Tv[tid];
        if (tv >= 2) v = bsum[tid] / (float)tv;
    }
    #pragma unroll
    for (int m = 1; m < 64; m <<= 1) v += __shfl_xor(v, m);
    if (tid == 0) out[0] = v / 32.0f;
}

extern "C" void kernel_launch(void* const* d_in, const int* in_sizes, int n_in,
                              void* d_out, int out_size, void* d_ws, size_t ws_size,
                              hipStream_t stream) {
    const float* eeg  = (const float*)d_in[0];
    const float* eye  = (const float*)d_in[1];
    const int*   mask = (const int*)d_in[2];
    const float* Weeg = (const float*)d_in[3];
    const float* Weye = (const float*)d_in[4];
    float* out = (float*)d_out;

    char* ws = (char*)d_ws;
    short* e_bf  = (short*)(ws);                       // 16 MiB
    short* v_bf  = (short*)(ws + 16777216);            // 16 MiB
    short* wbf   = (short*)(ws + 33554432);            // 256 KiB
    int*   rank  = (int*)  (ws + 33816576);            // 128 KiB
    int*   idx   = (int*)  (ws + 33947648);            // 128 KiB
    float* cb    = (float*)(ws + 34078720);            // 128 KiB
    float* psum  = (float*)(ws + 34209792);            // 512 KiB (32 b x 4 slices x 1024 i)
    float* pmax  = (float*)(ws + 34734080);            // 128 KiB
    int*   Tv    = (int*)  (ws + 34865152);            // 128 B
    float* bsum  = (float*)(ws + 34865280);            // 128 B

    prep_kernel<<<544, 256, 0, stream>>>(Weeg, Weye, mask, wbf, rank, idx, Tv, cb, bsum);
    proj_kernel<<<dim3(512, 2), 256, 0, stream>>>(eeg, eye, wbf, e_bf, v_bf);
    loss_kernel<<<1024, 256, 0, stream>>>(e_bf, v_bf, cb, psum);
    pos_kernel<<<2048, 256, 0, stream>>>(e_bf, v_bf, mask, rank, idx, Tv, pmax);
    reduce_kernel<<<128, 256, 0, stream>>>(psum, pmax, mask, bsum);
    final_kernel<<<1, 64, 0, stream>>>(bsum, Tv, out);
}

// Round 12
// 158.895 us; speedup vs baseline: 1.2958x; 1.0314x over previous
//
#include <hip/hip_runtime.h>
#include <hip/hip_bf16.h>

// B=32, T=1024, D=256 fixed by the reference problem.
typedef __attribute__((ext_vector_type(8))) short bf16x8;
typedef __attribute__((ext_vector_type(4))) float f32x4;

#define INVT (1.0f/0.07f)

static __device__ __forceinline__ short f2bf(float f){
    unsigned int u = __float_as_uint(f);
    unsigned int r = (u + 0x7fffu + ((u >> 16) & 1u)) >> 16;
    return (short)r;
}
static __device__ __forceinline__ float bf2f(short s){
    return __uint_as_float(((unsigned int)(unsigned short)s) << 16);
}

// async global->LDS, 16B per lane; LDS dest = wave-uniform base + lane*16
static __device__ __forceinline__ void gld16(const void* g, void* l){
    __builtin_amdgcn_global_load_lds(
        (const __attribute__((address_space(1))) unsigned int*)g,
        (__attribute__((address_space(3))) unsigned int*)l, 16, 0, 0);
}

// ---- prep: blocks 0..511 convert W to bf16; blocks 512..543 per-batch rank scan + zero bsum
__global__ __launch_bounds__(256) void prep_kernel(const float* __restrict__ Weeg,
                                                   const float* __restrict__ Weye,
                                                   const int* __restrict__ mask,
                                                   short* __restrict__ Wout,
                                                   int* __restrict__ rank,
                                                   int* __restrict__ idx,
                                                   int* __restrict__ Tv,
                                                   float* __restrict__ cb,
                                                   float* __restrict__ bsum){
    __shared__ int ssum[256];
    int tid = threadIdx.x;
    if (blockIdx.x < 512){
        int i = blockIdx.x * 256 + tid;
        float v = (i < 65536) ? Weeg[i] : Weye[i - 65536];
        Wout[i] = f2bf(v);
        return;
    }
    int b = blockIdx.x - 512;
    if (tid == 0) bsum[b] = 0.f;
    int local[4]; int s = 0;
    #pragma unroll
    for (int q = 0; q < 4; ++q){
        int t = tid*4 + q;
        local[q] = (mask[b*1024 + t] > 0) ? 1 : 0;
        s += local[q];
    }
    ssum[tid] = s;
    __syncthreads();
    for (int off = 1; off < 256; off <<= 1){
        int add = (tid >= off) ? ssum[tid - off] : 0;
        __syncthreads();
        ssum[tid] += add;
        __syncthreads();
    }
    int run = ssum[tid] - s;
    #pragma unroll
    for (int q = 0; q < 4; ++q){
        int t = tid*4 + q;
        int g = b*1024 + t;
        run += local[q];
        rank[g] = run - 1;
        cb[g]   = local[q] ? 0.0f : -1e9f;
        if (local[q]) idx[b*1024 + run - 1] = t;
    }
    if (tid == 255) Tv[b] = ssum[255];
}

// ---- fused projection + L2 normalize, both modalities (blockIdx.y selects).
// Double-buffered W staging (2 x 32KB), 4 chunks of 64 W-rows, drains overlapped.
// Dense epilogue via XOR-swizzled per-wave LDS transpose bounce (conflict-free)
// -> coalesced 16B/lane stores.
__global__ __launch_bounds__(256, 2) void proj_kernel(const float* __restrict__ Aeeg,
                                                      const float* __restrict__ Aeye,
                                                      const short* __restrict__ Wbf,
                                                      short* __restrict__ Eout,
                                                      short* __restrict__ Vout){
    __shared__ short sW[2][64 * 256];   // 2 x 32KB, XOR-swizzled in 16B blocks
    int sel = blockIdx.y;
    const float* A   = sel ? Aeye : Aeeg;
    const short* W   = Wbf + sel * 65536;
    short*       Out = sel ? Vout : Eout;

    int tid = threadIdx.x;
    int w = tid >> 6, lane = tid & 63;
    int l15 = lane & 15, lq = lane >> 4;
    int kb  = lq * 8;
    int row0 = blockIdx.x * 64;

    int ro   = lane >> 5;
    int cs   = lane & 31;
    int s7   = l15 & 7;

    // issue chunk 0 (W rows 0..63) -> buf0 and chunk 1 (64..127) -> buf1
    #pragma unroll
    for (int p = 0; p < 8; ++p){
        int rr = (p*2 + ro) & 7;
        gld16(W + (size_t)(w*16 + p*2 + ro)*256 + (cs ^ rr)*8,
              &sW[0][(w*16 + p*2) * 256]);
    }
    #pragma unroll
    for (int p = 0; p < 8; ++p){
        int rr = (p*2 + ro) & 7;
        gld16(W + (size_t)(64 + w*16 + p*2 + ro)*256 + (cs ^ rr)*8,
              &sW[1][(w*16 + p*2) * 256]);
    }

    // X-row fragments (B-operand), f32 -> bf16 (HBM; drains with chunk0/1)
    bf16x8 xf[8];
    {
        const float* ap = A + (size_t)(row0 + w*16 + l15) * 256 + kb;
        #pragma unroll
        for (int g = 0; g < 8; ++g){
            float4 x0 = *(const float4*)(ap + g*32);
            float4 x1 = *(const float4*)(ap + g*32 + 4);
            bf16x8 t;
            t[0]=f2bf(x0.x); t[1]=f2bf(x0.y); t[2]=f2bf(x0.z); t[3]=f2bf(x0.w);
            t[4]=f2bf(x1.x); t[5]=f2bf(x1.y); t[6]=f2bf(x1.z); t[7]=f2bf(x1.w);
            xf[g] = t;
        }
    }

    f32x4 acc[16];
    #pragma unroll
    for (int q = 0; q < 16; ++q) acc[q] = (f32x4){0.f,0.f,0.f,0.f};

    __syncthreads();   // c0, c1, xf ready

    #pragma unroll
    for (int nt = 0; nt < 4; ++nt){
        f32x4 c = acc[nt];
        int rbase = (nt*16 + l15) * 256;
        #pragma unroll
        for (int g = 0; g < 8; ++g){
            bf16x8 wf = *(const bf16x8*)&sW[0][rbase + (((g*4 + lq) ^ s7) << 3)];
            c = __builtin_amdgcn_mfma_f32_16x16x32_bf16(wf, xf[g], c, 0, 0, 0);
        }
        acc[nt] = c;
    }

    __syncthreads();

    #pragma unroll
    for (int p = 0; p < 8; ++p){
        int rr = (p*2 + ro) & 7;
        gld16(W + (size_t)(128 + w*16 + p*2 + ro)*256 + (cs ^ rr)*8,
              &sW[0][(w*16 + p*2) * 256]);
    }
    #pragma unroll
    for (int nt = 0; nt < 4; ++nt){
        f32x4 c = acc[4 + nt];
        int rbase = (nt*16 + l15) * 256;
        #pragma unroll
        for (int g = 0; g < 8; ++g){
            bf16x8 wf = *(const bf16x8*)&sW[1][rbase + (((g*4 + lq) ^ s7) << 3)];
            c = __builtin_amdgcn_mfma_f32_16x16x32_bf16(wf, xf[g], c, 0, 0, 0);
        }
        acc[4 + nt] = c;
    }

    __syncthreads();

    #pragma unroll
    for (int p = 0; p < 8; ++p){
        int rr = (p*2 + ro) & 7;
        gld16(W + (size_t)(192 + w*16 + p*2 + ro)*256 + (cs ^ rr)*8,
              &sW[1][(w*16 + p*2) * 256]);
    }
    #pragma unroll
    for (int nt = 0; nt < 4; ++nt){
        f32x4 c = acc[8 + nt];
        int rbase = (nt*16 + l15) * 256;
        #pragma unroll
        for (int g = 0; g < 8; ++g){
            bf16x8 wf = *(const bf16x8*)&sW[0][rbase + (((g*4 + lq) ^ s7) << 3)];
            c = __builtin_amdgcn_mfma_f32_16x16x32_bf16(wf, xf[g], c, 0, 0, 0);
        }
        acc[8 + nt] = c;
    }

    __syncthreads();

    #pragma unroll
    for (int nt = 0; nt < 4; ++nt){
        f32x4 c = acc[12 + nt];
        int rbase = (nt*16 + l15) * 256;
        #pragma unroll
        for (int g = 0; g < 8; ++g){
            bf16x8 wf = *(const bf16x8*)&sW[1][rbase + (((g*4 + lq) ^ s7) << 3)];
            c = __builtin_amdgcn_mfma_f32_16x16x32_bf16(wf, xf[g], c, 0, 0, 0);
        }
        acc[12 + nt] = c;
    }

    float ss = 0.f;
    #pragma unroll
    for (int q = 0; q < 16; ++q){
        #pragma unroll
        for (int r = 0; r < 4; ++r){ float x = acc[q][r]; ss += x*x; }
    }
    ss += __shfl_xor(ss, 16);
    ss += __shfl_xor(ss, 32);
    float scale = 1.0f / fmaxf(sqrtf(ss), 1e-12f);

    // dense epilogue via XOR-swizzled per-wave transpose bounce through buf0.
    // Writer: logical 16B-block c of row r stored at LDS block c ^ (r&7)
    // (r&7 == l15&7 for this lane's row) -> write bank spread 8x2 = free.
    short* twrow = &sW[0][(w*16 + l15) * 256];
    #pragma unroll
    for (int q = 0; q < 16; ++q){
        short4 pk;
        pk.x = f2bf(acc[q][0] * scale);
        pk.y = f2bf(acc[q][1] * scale);
        pk.z = f2bf(acc[q][2] * scale);
        pk.w = f2bf(acc[q][3] * scale);
        int c    = (q >> 2) * 64 + (q & 3) * 16 + lq*4;   // logical column (shorts)
        int blk  = (c >> 3) ^ s7;                          // swizzled 16B block
        *(short4*)(twrow + blk*8 + (c & 7)) = pk;
    }
    // Reader: global row r_abs = w*16 + p*2 + (lane>>5), global block g = lane&31;
    // read LDS block g ^ (r_abs&7)  -> permutation per row, conflict-free.
    short* op = Out + (size_t)(row0 + w*16) * 256;
    #pragma unroll
    for (int p = 0; p < 8; ++p){
        int rloc = p*2 + (lane >> 5);
        int gblk = lane & 31;
        const short* tr = &sW[0][(w*16 + rloc) * 256 + ((gblk ^ (rloc & 7)) * 8)];
        *(int4*)(op + rloc*256 + gblk*8) = *(const int4*)tr;
    }
}

// ---- loss: block = 128i x 256j; wave = 32 i-rows. E A-frags loaded ONCE per
// 256-j sweep. V staged in 4 chunks of 64 j-rows x K=256 (32KB) through a
// 2x32KB double buffer; 4 barriers, drains overlapped. XCD-pinned grid 1024.
// Epilogue -> psum[b][js][i] (4 slices), dense stores.
__global__ __launch_bounds__(256, 2) void loss_kernel(const short* __restrict__ E,
                                                      const short* __restrict__ V,
                                                      const float* __restrict__ cb,
                                                      float* __restrict__ psum){
    __shared__ short sV[2][64 * 256];   // 2 x 32KB, XOR-swizzled in 16B blocks
    __shared__ float sRed[4][32];

    int n  = blockIdx.x;
    int m  = n >> 3;
    int b  = ((m >> 5) << 3) | (n & 7);
    int lm = m & 31;
    int i0 = (lm >> 2) * 128;
    int js = lm & 3;
    int j0 = js * 256;

    int tid = threadIdx.x;
    int w = tid >> 6, lane = tid & 63;
    int l15 = lane & 15, lq = lane >> 4;
    int kb = lq * 8;
    int s7 = l15 & 7;
    int ro = lane >> 5;
    int cs = lane & 31;

    const short* Vrow = V + ((size_t)b*1024 + j0 + w*16 + ro) * 256;

    // issue h0c0 (j rows 0..63) -> buf0
    #pragma unroll
    for (int p = 0; p < 8; ++p){
        int rr = (p*2 + ro) & 7;
        gld16(Vrow + (size_t)(p*2)*256 + (size_t)((cs ^ rr) * 8),
              &sV[0][(w*16 + p*2) * 256]);
    }

    // A-frags: 2 sets x 8 -> 32 i-rows, register-resident, loaded once
    bf16x8 af[2][8];
    {
        const short* ep = E + ((size_t)b*1024 + i0 + w*32 + l15) * 256 + kb;
        #pragma unroll
        for (int g = 0; g < 8; ++g){
            af[0][g] = *(const bf16x8*)(ep + g*32);
            af[1][g] = *(const bf16x8*)(ep + 16*256 + g*32);
        }
    }

    float cbv0[8];
    #pragma unroll
    for (int ct = 0; ct < 8; ++ct)
        cbv0[ct] = cb[b*1024 + j0 + ct*16 + l15];

    f32x4 acc[2][8];
    #pragma unroll
    for (int s = 0; s < 2; ++s)
        #pragma unroll
        for (int ct = 0; ct < 8; ++ct) acc[s][ct] = (f32x4){0.f,0.f,0.f,0.f};
    float ls[2][4] = {{0.f,0.f,0.f,0.f},{0.f,0.f,0.f,0.f}};

    __syncthreads();    // publish h0c0

    // issue h0c1 (64..127) -> buf1
    #pragma unroll
    for (int p = 0; p < 8; ++p){
        int rr = (p*2 + ro) & 7;
        gld16(Vrow + (size_t)(64 + p*2)*256 + (size_t)((cs ^ rr) * 8),
              &sV[1][(w*16 + p*2) * 256]);
    }
    // compute h0c0 from buf0
    #pragma unroll
    for (int jt = 0; jt < 4; ++jt){
        bf16x8 bf[8];
        #pragma unroll
        for (int g = 0; g < 8; ++g)
            bf[g] = *(const bf16x8*)&sV[0][(jt*16 + l15)*256 + (((g*4 + lq) ^ s7) << 3)];
        #pragma unroll
        for (int g = 0; g < 8; ++g){
            acc[0][jt] = __builtin_amdgcn_mfma_f32_16x16x32_bf16(af[0][g], bf[g], acc[0][jt], 0, 0, 0);
            acc[1][jt] = __builtin_amdgcn_mfma_f32_16x16x32_bf16(af[1][g], bf[g], acc[1][jt], 0, 0, 0);
        }
    }

    __syncthreads();    // publish h0c1 (drain overlapped by h0c0 compute)

    // issue h1c0 (128..191) -> buf0
    #pragma unroll
    for (int p = 0; p < 8; ++p){
        int rr = (p*2 + ro) & 7;
        gld16(Vrow + (size_t)(128 + p*2)*256 + (size_t)((cs ^ rr) * 8),
              &sV[0][(w*16 + p*2) * 256]);
    }
    // compute h0c1 from buf1
    #pragma unroll
    for (int jt = 0; jt < 4; ++jt){
        bf16x8 bf[8];
        #pragma unroll
        for (int g = 0; g < 8; ++g)
            bf[g] = *(const bf16x8*)&sV[1][(jt*16 + l15)*256 + (((g*4 + lq) ^ s7) << 3)];
        #pragma unroll
        for (int g = 0; g < 8; ++g){
            acc[0][4+jt] = __builtin_amdgcn_mfma_f32_16x16x32_bf16(af[0][g], bf[g], acc[0][4+jt], 0, 0, 0);
            acc[1][4+jt] = __builtin_amdgcn_mfma_f32_16x16x32_bf16(af[1][g], bf[g], acc[1][4+jt], 0, 0, 0);
        }
    }
    // epilogue-accumulate half0 (overlaps h1c0 drain), then reset acc
    #pragma unroll
    for (int s = 0; s < 2; ++s){
        #pragma unroll
        for (int r = 0; r < 4; ++r){
            float a0 = 0.f;
            #pragma unroll
            for (int ct = 0; ct < 8; ++ct)
                a0 += __expf(fmaf(acc[s][ct][r], INVT, cbv0[ct]));
            ls[s][r] += a0;
        }
    }
    #pragma unroll
    for (int s = 0; s < 2; ++s)
        #pragma unroll
        for (int ct = 0; ct < 8; ++ct) acc[s][ct] = (f32x4){0.f,0.f,0.f,0.f};

    float cbv1[8];
    #pragma unroll
    for (int ct = 0; ct < 8; ++ct)
        cbv1[ct] = cb[b*1024 + j0 + 128 + ct*16 + l15];

    __syncthreads();    // publish h1c0

    // issue h1c1 (192..255) -> buf1
    #pragma unroll
    for (int p = 0; p < 8; ++p){
        int rr = (p*2 + ro) & 7;
        gld16(Vrow + (size_t)(192 + p*2)*256 + (size_t)((cs ^ rr) * 8),
              &sV[1][(w*16 + p*2) * 256]);
    }
    // compute h1c0 from buf0
    #pragma unroll
    for (int jt = 0; jt < 4; ++jt){
        bf16x8 bf[8];
        #pragma unroll
        for (int g = 0; g < 8; ++g)
            bf[g] = *(const bf16x8*)&sV[0][(jt*16 + l15)*256 + (((g*4 + lq) ^ s7) << 3)];
        #pragma unroll
        for (int g = 0; g < 8; ++g){
            acc[0][jt] = __builtin_amdgcn_mfma_f32_16x16x32_bf16(af[0][g], bf[g], acc[0][jt], 0, 0, 0);
            acc[1][jt] = __builtin_amdgcn_mfma_f32_16x16x32_bf16(af[1][g], bf[g], acc[1][jt], 0, 0, 0);
        }
    }

    __syncthreads();    // publish h1c1 (drain overlapped by h1c0 compute)

    // compute h1c1 from buf1
    #pragma unroll
    for (int jt = 0; jt < 4; ++jt){
        bf16x8 bf[8];
        #pragma unroll
        for (int g = 0; g < 8; ++g)
            bf[g] = *(const bf16x8*)&sV[1][(jt*16 + l15)*256 + (((g*4 + lq) ^ s7) << 3)];
        #pragma unroll
        for (int g = 0; g < 8; ++g){
            acc[0][4+jt] = __builtin_amdgcn_mfma_f32_16x16x32_bf16(af[0][g], bf[g], acc[0][4+jt], 0, 0, 0);
            acc[1][4+jt] = __builtin_amdgcn_mfma_f32_16x16x32_bf16(af[1][g], bf[g], acc[1][4+jt], 0, 0, 0);
        }
    }
    // epilogue-accumulate half1
    #pragma unroll
    for (int s = 0; s < 2; ++s){
        #pragma unroll
        for (int r = 0; r < 4; ++r){
            float a1 = 0.f;
            #pragma unroll
            for (int ct = 0; ct < 8; ++ct)
                a1 += __expf(fmaf(acc[s][ct][r], INVT, cbv1[ct]));
            ls[s][r] += a1;
        }
    }

    // reduce over the 16 lanes sharing each row; dense store via LDS bounce
    #pragma unroll
    for (int s = 0; s < 2; ++s){
        #pragma unroll
        for (int r = 0; r < 4; ++r){
            float v = ls[s][r];
            #pragma unroll
            for (int mm = 1; mm < 16; mm <<= 1)
                v += __shfl_xor(v, mm);
            ls[s][r] = v;
        }
    }
    if (l15 == 0){
        #pragma unroll
        for (int s = 0; s < 2; ++s)
            #pragma unroll
            for (int r = 0; r < 4; ++r)
                sRed[w][s*16 + lq*4 + r] = ls[s][r];
    }
    float* pp = psum + (((size_t)(b*4 + js)) << 10);
    if (lane < 32) pp[i0 + w*32 + lane] = sRed[w][lane];
}

// ---- banded positive max: one 16-lane group per row, <=5 candidate cols via idx.
__global__ __launch_bounds__(256) void pos_kernel(const short* __restrict__ E,
                                                  const short* __restrict__ V,
                                                  const int* __restrict__ mask,
                                                  const int* __restrict__ rank,
                                                  const int* __restrict__ idx,
                                                  const int* __restrict__ Tv,
                                                  float* __restrict__ pmax){
    int tid = threadIdx.x;
    int gl  = tid & 15;
    int rf  = (blockIdx.x * 256 + tid) >> 4;   // 0..32767
    int b   = rf >> 10;
    if (mask[rf] <= 0) return;

    int ri = rank[rf];
    int tv = Tv[b];
    int lo = ri - 2; if (lo < 0) lo = 0;
    int hi = ri + 2; if (hi > tv - 1) hi = tv - 1;

    const short* epp = E + (size_t)rf * 256 + gl * 16;
    float ev[16];
    {
        bf16x8 e0 = *(const bf16x8*)epp;
        bf16x8 e1 = *(const bf16x8*)(epp + 8);
        #pragma unroll
        for (int k = 0; k < 8; ++k){ ev[k] = bf2f(e0[k]); ev[8+k] = bf2f(e1[k]); }
    }
    float pm = -1e30f;
    for (int r = lo; r <= hi; ++r){
        int j = idx[b*1024 + r];
        const short* vpp = V + ((size_t)(b*1024) + j) * 256 + gl * 16;
        bf16x8 v0 = *(const bf16x8*)vpp;
        bf16x8 v1 = *(const bf16x8*)(vpp + 8);
        float s = 0.f;
        #pragma unroll
        for (int k = 0; k < 8; ++k){
            s = fmaf(ev[k],   bf2f(v0[k]), s);
            s = fmaf(ev[8+k], bf2f(v1[k]), s);
        }
        s += __shfl_xor(s, 1);
        s += __shfl_xor(s, 2);
        s += __shfl_xor(s, 4);
        s += __shfl_xor(s, 8);
        pm = fmaxf(pm, s);
    }
    if (gl == 0) pmax[rf] = pm * INVT;
}

// ---- partial reduce: 4 blocks per b, each thread one i; coalesced psum reads.
__global__ __launch_bounds__(256) void reduce_kernel(const float* __restrict__ psum,
                                                     const float* __restrict__ pmax,
                                                     const int* __restrict__ mask,
                                                     float* __restrict__ bsum){
    int b  = blockIdx.x >> 2;
    int i  = (blockIdx.x & 3) * 256 + threadIdx.x;
    int g  = b*1024 + i;
    float a = 0.f;
    if (mask[g] > 0){
        const float* pp = psum + ((size_t)b << 12);
        float ps = pp[i] + pp[i + 1024] + pp[i + 2048] + pp[i + 3072];
        a = logf(ps) - pmax[g];
    }
    #pragma unroll
    for (int m = 1; m < 64; m <<= 1) a += __shfl_xor(a, m);
    if ((threadIdx.x & 63) == 0 && a != 0.f) atomicAdd(&bsum[b], a);
}

// ---- final: out = sum_b (Tv>=2 ? bsum/Tv : 0) / 32
__global__ void final_kernel(const float* __restrict__ bsum,
                             const int* __restrict__ Tv,
                             float* __restrict__ out){
    int tid = threadIdx.x;
    float v = 0.f;
    if (tid < 32){
        int tv = Tv[tid];
        if (tv >= 2) v = bsum[tid] / (float)tv;
    }
    #pragma unroll
    for (int m = 1; m < 64; m <<= 1) v += __shfl_xor(v, m);
    if (tid == 0) out[0] = v / 32.0f;
}

extern "C" void kernel_launch(void* const* d_in, const int* in_sizes, int n_in,
                              void* d_out, int out_size, void* d_ws, size_t ws_size,
                              hipStream_t stream) {
    const float* eeg  = (const float*)d_in[0];
    const float* eye  = (const float*)d_in[1];
    const int*   mask = (const int*)d_in[2];
    const float* Weeg = (const float*)d_in[3];
    const float* Weye = (const float*)d_in[4];
    float* out = (float*)d_out;

    char* ws = (char*)d_ws;
    short* e_bf  = (short*)(ws);                       // 16 MiB
    short* v_bf  = (short*)(ws + 16777216);            // 16 MiB
    short* wbf   = (short*)(ws + 33554432);            // 256 KiB
    int*   rank  = (int*)  (ws + 33816576);            // 128 KiB
    int*   idx   = (int*)  (ws + 33947648);            // 128 KiB
    float* cb    = (float*)(ws + 34078720);            // 128 KiB
    float* psum  = (float*)(ws + 34209792);            // 512 KiB (32 b x 4 slices x 1024 i)
    float* pmax  = (float*)(ws + 34734080);            // 128 KiB
    int*   Tv    = (int*)  (ws + 34865152);            // 128 B
    float* bsum  = (float*)(ws + 34865280);            // 128 B

    prep_kernel<<<544, 256, 0, stream>>>(Weeg, Weye, mask, wbf, rank, idx, Tv, cb, bsum);
    proj_kernel<<<dim3(512, 2), 256, 0, stream>>>(eeg, eye, wbf, e_bf, v_bf);
    loss_kernel<<<1024, 256, 0, stream>>>(e_bf, v_bf, cb, psum);
    pos_kernel<<<2048, 256, 0, stream>>>(e_bf, v_bf, mask, rank, idx, Tv, pmax);
    reduce_kernel<<<128, 256, 0, stream>>>(psum, pmax, mask, bsum);
    final_kernel<<<1, 64, 0, stream>>>(bsum, Tv, out);
}